// Round 1
// baseline (1629.595 us; speedup 1.0000x reference)
//
#include <hip/hip_runtime.h>
#include <hip/hip_bf16.h>

// Problem constants
#define BB 32
#define C1 128
#define HH 32
#define WW 32
#define SS 1024        // H*W
#define DD 256
#define NHH 8
#define DHH 32
#define KSEL 66        // ceil(0.0005*128*32*32)
#define TRIPLE 768

// ---------------------------------------------------------------------------
// Kernel 1: 9x9 conv (cross-correlation, pad 4) + ReLU.  A: (B, C1, 32, 32)
// ---------------------------------------------------------------------------
__global__ __launch_bounds__(256) void conv_relu_kernel(
    const float* __restrict__ x, const float* __restrict__ w, float* __restrict__ A) {
  const int bx = blockIdx.x;              // b*128 + c
  const int b = bx >> 7, c = bx & 127;
  __shared__ float xs[40 * 40];
  __shared__ float ws[81];
  const int t = threadIdx.x;
  for (int i = t; i < 1600; i += 256) {
    int r = i / 40, cc = i - r * 40;
    int gi = r - 4, gj = cc - 4;
    float v = 0.f;
    if (gi >= 0 && gi < 32 && gj >= 0 && gj < 32) v = x[(size_t)b * 1024 + gi * 32 + gj];
    xs[i] = v;
  }
  if (t < 81) ws[t] = w[(size_t)c * 81 + t];
  __syncthreads();
#pragma unroll
  for (int i = 0; i < 4; ++i) {
    int p = t + i * 256;
    int r = p >> 5, col = p & 31;
    float acc = 0.f;
#pragma unroll
    for (int u = 0; u < 9; ++u)
#pragma unroll
      for (int v = 0; v < 9; ++v)
        acc += xs[(r + u) * 40 + col + v] * ws[u * 9 + v];
    A[(size_t)bx * 1024 + p] = fmaxf(acc, 0.f);
  }
}

// ---------------------------------------------------------------------------
// Kernel 2: exact 66th-largest per batch via 3-level radix select on float
// bits (values are >= 0 so uint ordering == float ordering). Also global max.
// ---------------------------------------------------------------------------
__global__ __launch_bounds__(1024) void select_thresh_kernel(
    const float* __restrict__ A, float* __restrict__ thresh, float* __restrict__ gmaxp) {
  const int b = blockIdx.x;
  const float* Ab = A + (size_t)b * (C1 * SS);
  __shared__ unsigned hist[2048];
  __shared__ unsigned s_sel, s_rank, s_gbits;
  const int tid = threadIdx.x;
  if (tid == 0) s_gbits = 0u;
  for (int i = tid; i < 2048; i += 1024) hist[i] = 0u;
  __syncthreads();
  unsigned lmax = 0u;
  for (int i = tid; i < C1 * SS; i += 1024) {
    unsigned bits = __float_as_uint(Ab[i]);
    if (bits > lmax) lmax = bits;
    atomicAdd(&hist[bits >> 21], 1u);
  }
  atomicMax(&s_gbits, lmax);
  __syncthreads();
  if (tid == 0) {
    unsigned r = KSEL, cum = 0u;
    int bin = 2048;
    while (bin > 0) { --bin; cum += hist[bin]; if (cum >= r) break; }
    s_sel = (unsigned)bin;
    s_rank = r - (cum - hist[bin]);
  }
  __syncthreads();
  const unsigned v1 = s_sel;
  for (int i = tid; i < 2048; i += 1024) hist[i] = 0u;
  __syncthreads();
  for (int i = tid; i < C1 * SS; i += 1024) {
    unsigned bits = __float_as_uint(Ab[i]);
    if ((bits >> 21) == v1) atomicAdd(&hist[(bits >> 10) & 0x7FFu], 1u);
  }
  __syncthreads();
  if (tid == 0) {
    unsigned r = s_rank, cum = 0u;
    int bin = 2048;
    while (bin > 0) { --bin; cum += hist[bin]; if (cum >= r) break; }
    s_sel = (unsigned)bin;
    s_rank = r - (cum - hist[bin]);
  }
  __syncthreads();
  const unsigned v2 = s_sel;
  const unsigned pref = (v1 << 11) | v2;
  for (int i = tid; i < 1024; i += 1024) hist[i] = 0u;
  __syncthreads();
  for (int i = tid; i < C1 * SS; i += 1024) {
    unsigned bits = __float_as_uint(Ab[i]);
    if ((bits >> 10) == pref) atomicAdd(&hist[bits & 0x3FFu], 1u);
  }
  __syncthreads();
  if (tid == 0) {
    unsigned r = s_rank, cum = 0u;
    int bin = 1024;
    while (bin > 0) { --bin; cum += hist[bin]; if (cum >= r) break; }
    unsigned tb = (v1 << 21) | (v2 << 10) | (unsigned)bin;
    thresh[b] = __uint_as_float(tb);
    gmaxp[b] = __uint_as_float(s_gbits);
  }
}

// ---------------------------------------------------------------------------
// Kernel 3: per-pixel masked channel top-8 (jax tie-break: desc value, ties ->
// lower index; zero slots fill with smallest unused channel indices).
// Writes topi (as float), scatters sparse_weights, emits kept idx/val lists.
// ---------------------------------------------------------------------------
__global__ __launch_bounds__(256) void topk_pixel_kernel(
    const float* __restrict__ A, const float* __restrict__ thresh,
    const float* __restrict__ gmaxp, float* __restrict__ out_sw,
    float* __restrict__ out_topi, int* __restrict__ kidx, float* __restrict__ kval) {
  const int bx = blockIdx.x;              // b*4 + chunk
  const int b = bx >> 2;
  const int p = ((bx & 3) << 8) + threadIdx.x;
  const float th = thresh[b];
  const float gm = gmaxp[b];
  const float scale = gm > 0.f ? 1.f / gm : 0.f;
  const float* Ab = A + (size_t)b * (C1 * SS) + p;

  float tv0 = -1.f, tv1 = -1.f, tv2 = -1.f, tv3 = -1.f, tv4 = -1.f, tv5 = -1.f, tv6 = -1.f, tv7 = -1.f;
  int ti0 = 0, ti1 = 0, ti2 = 0, ti3 = 0, ti4 = 0, ti5 = 0, ti6 = 0, ti7 = 0;
  int cnt = 0;
#pragma unroll 1
  for (int c = 0; c < C1; ++c) {
    float v = Ab[(size_t)c << 10];
    if (v >= th) {
      ++cnt;
      // sorted-desc insertion, strict > keeps equal values in scan (index) order
      bool s7 = v > tv6, p7 = (v > tv7) && !s7;
      float n7 = p7 ? v : (s7 ? tv6 : tv7); int m7 = p7 ? c : (s7 ? ti6 : ti7);
      bool s6 = v > tv5, p6 = (v > tv6) && !s6;
      float n6 = p6 ? v : (s6 ? tv5 : tv6); int m6 = p6 ? c : (s6 ? ti5 : ti6);
      bool s5 = v > tv4, p5 = (v > tv5) && !s5;
      float n5 = p5 ? v : (s5 ? tv4 : tv5); int m5 = p5 ? c : (s5 ? ti4 : ti5);
      bool s4 = v > tv3, p4 = (v > tv4) && !s4;
      float n4 = p4 ? v : (s4 ? tv3 : tv4); int m4 = p4 ? c : (s4 ? ti3 : ti4);
      bool s3 = v > tv2, p3 = (v > tv3) && !s3;
      float n3 = p3 ? v : (s3 ? tv2 : tv3); int m3 = p3 ? c : (s3 ? ti2 : ti3);
      bool s2 = v > tv1, p2 = (v > tv2) && !s2;
      float n2 = p2 ? v : (s2 ? tv1 : tv2); int m2 = p2 ? c : (s2 ? ti1 : ti2);
      bool s1 = v > tv0, p1 = (v > tv1) && !s1;
      float n1 = p1 ? v : (s1 ? tv0 : tv1); int m1 = p1 ? c : (s1 ? ti0 : ti1);
      bool p0 = v > tv0;
      float n0 = p0 ? v : tv0; int m0 = p0 ? c : ti0;
      tv7 = n7; ti7 = m7; tv6 = n6; ti6 = m6; tv5 = n5; ti5 = m5; tv4 = n4; ti4 = m4;
      tv3 = n3; ti3 = m3; tv2 = n2; ti2 = m2; tv1 = n1; ti1 = m1; tv0 = n0; ti0 = m0;
    }
  }
  const int m = cnt < 8 ? cnt : 8;
  // fill empty slots with smallest channel indices not used by survivors
  int fv[8] = {ti0, ti1, ti2, ti3, ti4, ti5, ti6, ti7};
  int fill_c = 0;
#pragma unroll
  for (int j = 0; j < 8; ++j) {
    if (j >= m) {
      bool adv = true;
      while (adv) {
        adv = false;
#pragma unroll
        for (int t2 = 0; t2 < 8; ++t2)
          if (t2 < m && fv[t2] == fill_c) adv = true;
        if (adv) ++fill_c;
      }
      fv[j] = fill_c;
      ++fill_c;
    }
  }
  ti0 = fv[0]; ti1 = fv[1]; ti2 = fv[2]; ti3 = fv[3]; ti4 = fv[4]; ti5 = fv[5]; ti6 = fv[6]; ti7 = fv[7];
  if (m <= 0) tv0 = 0.f; if (m <= 1) tv1 = 0.f; if (m <= 2) tv2 = 0.f; if (m <= 3) tv3 = 0.f;
  if (m <= 4) tv4 = 0.f; if (m <= 5) tv5 = 0.f; if (m <= 6) tv6 = 0.f; if (m <= 7) tv7 = 0.f;

  const size_t pix = (size_t)b * SS + p;
  float* tp = out_topi + pix * 8;
  tp[0] = (float)ti0; tp[1] = (float)ti1; tp[2] = (float)ti2; tp[3] = (float)ti3;
  tp[4] = (float)ti4; tp[5] = (float)ti5; tp[6] = (float)ti6; tp[7] = (float)ti7;
  int* ki = kidx + pix * 8;
  ki[0] = ti0; ki[1] = ti1; ki[2] = ti2; ki[3] = ti3; ki[4] = ti4; ki[5] = ti5; ki[6] = ti6; ki[7] = ti7;
  float* kv = kval + pix * 8;
  float sv0 = tv0 * scale, sv1 = tv1 * scale, sv2 = tv2 * scale, sv3 = tv3 * scale;
  float sv4 = tv4 * scale, sv5 = tv5 * scale, sv6 = tv6 * scale, sv7 = tv7 * scale;
  kv[0] = sv0; kv[1] = sv1; kv[2] = sv2; kv[3] = sv3; kv[4] = sv4; kv[5] = sv5; kv[6] = sv6; kv[7] = sv7;
  float* sw = out_sw + pix * C1;
  if (m > 0) sw[ti0] = sv0; if (m > 1) sw[ti1] = sv1; if (m > 2) sw[ti2] = sv2; if (m > 3) sw[ti3] = sv3;
  if (m > 4) sw[ti4] = sv4; if (m > 5) sw[ti5] = sv5; if (m > 6) sw[ti6] = sv6; if (m > 7) sw[ti7] = sv7;
}

// ---------------------------------------------------------------------------
// Kernel 4: loc_emb(b,p,d) = PE(w,d) + sum_j kval[j]*emb[kidx[j], d]
// ---------------------------------------------------------------------------
__global__ __launch_bounds__(256) void loc_emb_kernel(
    const int* __restrict__ kidx, const float* __restrict__ kval,
    const float* __restrict__ emb, float* __restrict__ le) {
  const int pix = blockIdx.x;             // b*1024 + p
  const int d = threadIdx.x;
  const int w = pix & 31;
  const int i2 = d >> 1;
  const float div = expf((float)(2 * i2) * (-9.210340371976184f / 256.f));
  const float ang = (float)w * div;
  const float pe = (d & 1) ? cosf(ang) : sinf(ang);
  const int* ki = kidx + (size_t)pix * 8;
  const float* kv = kval + (size_t)pix * 8;
  float acc = pe;
#pragma unroll
  for (int j = 0; j < 8; ++j) acc += kv[j] * emb[(size_t)ki[j] * DD + d];
  le[(size_t)pix * DD + d] = acc;
}

// ---------------------------------------------------------------------------
// Kernel 5: QKV = LE(32768x256) @ in_proj_w^T(256x768) + b.  fp32 tiled GEMM.
// ---------------------------------------------------------------------------
__global__ __launch_bounds__(256) void qkv_gemm_kernel(
    const float* __restrict__ X, const float* __restrict__ W,
    const float* __restrict__ bias, float* __restrict__ Y) {
  __shared__ float Xs[16][65];
  __shared__ float Ws[16][65];
  const int m0 = blockIdx.x * 64;
  const int o0 = blockIdx.y * 64;
  const int t = threadIdx.x;
  const int tm = t >> 2, tk = (t & 3) << 2;
  const int ty = t >> 4, tx = t & 15;
  float acc[4][4];
#pragma unroll
  for (int i = 0; i < 4; ++i)
#pragma unroll
    for (int j = 0; j < 4; ++j) acc[i][j] = 0.f;
  for (int k0 = 0; k0 < DD; k0 += 16) {
    float4 xa = *(const float4*)&X[(size_t)(m0 + tm) * DD + k0 + tk];
    float4 wa = *(const float4*)&W[(size_t)(o0 + tm) * DD + k0 + tk];
    __syncthreads();
    Xs[tk + 0][tm] = xa.x; Xs[tk + 1][tm] = xa.y; Xs[tk + 2][tm] = xa.z; Xs[tk + 3][tm] = xa.w;
    Ws[tk + 0][tm] = wa.x; Ws[tk + 1][tm] = wa.y; Ws[tk + 2][tm] = wa.z; Ws[tk + 3][tm] = wa.w;
    __syncthreads();
#pragma unroll
    for (int k = 0; k < 16; ++k) {
      float a0 = Xs[k][ty * 4 + 0], a1 = Xs[k][ty * 4 + 1], a2 = Xs[k][ty * 4 + 2], a3 = Xs[k][ty * 4 + 3];
      float b0 = Ws[k][tx * 4 + 0], b1 = Ws[k][tx * 4 + 1], b2 = Ws[k][tx * 4 + 2], b3 = Ws[k][tx * 4 + 3];
      acc[0][0] += a0 * b0; acc[0][1] += a0 * b1; acc[0][2] += a0 * b2; acc[0][3] += a0 * b3;
      acc[1][0] += a1 * b0; acc[1][1] += a1 * b1; acc[1][2] += a1 * b2; acc[1][3] += a1 * b3;
      acc[2][0] += a2 * b0; acc[2][1] += a2 * b1; acc[2][2] += a2 * b2; acc[2][3] += a2 * b3;
      acc[3][0] += a3 * b0; acc[3][1] += a3 * b1; acc[3][2] += a3 * b2; acc[3][3] += a3 * b3;
    }
  }
#pragma unroll
  for (int i = 0; i < 4; ++i) {
    int n = m0 + ty * 4 + i;
#pragma unroll
    for (int j = 0; j < 4; ++j) {
      int o = o0 + tx * 4 + j;
      Y[(size_t)n * TRIPLE + o] = acc[i][j] + bias[o];
    }
  }
}

// ---------------------------------------------------------------------------
// Kernel 6: flash-style attention; accumulate sum over q of ctx rows into
// ctx_sum (B, 256).  One block per (b, head, q-chunk of 256 rows).
// ---------------------------------------------------------------------------
__global__ __launch_bounds__(256) void attn_kernel(
    const float* __restrict__ QKV, float* __restrict__ ctx_sum) {
  const int bx = blockIdx.x;
  const int b = bx >> 5, h = (bx >> 2) & 7, qc = bx & 3;
  const int t = threadIdx.x;
  const int qrow = qc * 256 + t;
  const size_t baseB = (size_t)b * SS * TRIPLE;
  const float* qp = QKV + baseB + (size_t)qrow * TRIPLE + h * DHH;
  float4 q[8];
#pragma unroll
  for (int j = 0; j < 8; ++j) q[j] = *(const float4*)(qp + j * 4);
  __shared__ float Kt[64][32];
  __shared__ float Vt[64][32];
  float mrun = -1e30f, l = 0.f;
  float acc[32];
#pragma unroll
  for (int d = 0; d < 32; ++d) acc[d] = 0.f;
  const float scale = 0.17677669529663687f;  // 1/sqrt(32)
  for (int tile = 0; tile < 16; ++tile) {
    __syncthreads();
#pragma unroll
    for (int i = 0; i < 2; ++i) {
      int f = t + i * 256;
      int row = f >> 3, comp = f & 7;
      const float* kp = QKV + baseB + (size_t)(tile * 64 + row) * TRIPLE + DD + h * DHH + comp * 4;
      *(float4*)&Kt[row][comp * 4] = *(const float4*)kp;
      *(float4*)&Vt[row][comp * 4] = *(const float4*)(kp + DD);
    }
    __syncthreads();
#pragma unroll 1
    for (int kk = 0; kk < 64; ++kk) {
      const float4* kr = (const float4*)&Kt[kk][0];
      float s = 0.f;
#pragma unroll
      for (int j = 0; j < 8; ++j) {
        float4 kj = kr[j];
        s += q[j].x * kj.x + q[j].y * kj.y + q[j].z * kj.z + q[j].w * kj.w;
      }
      s *= scale;
      float mn = fmaxf(mrun, s);
      float corr = __expf(mrun - mn);
      float p = __expf(s - mn);
      l = l * corr + p;
      const float* vr = &Vt[kk][0];
#pragma unroll
      for (int d = 0; d < 32; ++d) acc[d] = acc[d] * corr + p * vr[d];
      mrun = mn;
    }
  }
  const float invl = 1.f / l;
#pragma unroll
  for (int d = 0; d < 32; ++d) {
    float v = acc[d] * invl;
#pragma unroll
    for (int off = 32; off >= 1; off >>= 1) v += __shfl_xor(v, off);
    if ((t & 63) == 0) atomicAdd(&ctx_sum[b * DD + h * DHH + d], v);
  }
}

// ---------------------------------------------------------------------------
// Kernel 7: pooled(b,o) = bias[o] + sum_d (ctx_sum[b,d]/1024) * Wout[o,d]
// ---------------------------------------------------------------------------
__global__ __launch_bounds__(256) void pooled_kernel(
    const float* __restrict__ ctx_sum, const float* __restrict__ Wout,
    const float* __restrict__ bout, float* __restrict__ out) {
  const int b = blockIdx.x;
  const int o = threadIdx.x;
  __shared__ float mc[DD];
  mc[o] = ctx_sum[b * DD + o] * (1.f / 1024.f);
  __syncthreads();
  float acc = bout[o];
  const float* wr = Wout + (size_t)o * DD;
#pragma unroll 4
  for (int d = 0; d < DD; ++d) acc += mc[d] * wr[d];
  out[b * DD + o] = acc;
}

// ---------------------------------------------------------------------------
extern "C" void kernel_launch(void* const* d_in, const int* in_sizes, int n_in,
                              void* d_out, int out_size, void* d_ws, size_t ws_size,
                              hipStream_t stream) {
  const float* x = (const float*)d_in[0];
  const float* conv_w = (const float*)d_in[1];
  const float* emb = (const float*)d_in[2];
  const float* ipw = (const float*)d_in[3];
  const float* ipb = (const float*)d_in[4];
  const float* opw = (const float*)d_in[5];
  const float* opb = (const float*)d_in[6];

  float* out = (float*)d_out;
  float* out_pooled = out;                          // 32*256      = 8192
  float* out_sw = out + 8192;                       // 32*32*32*128 = 4194304
  float* out_topi = out + 8192 + 4194304;           // 32*32*32*8  = 262144

  // workspace layout (total ~146 MiB)
  char* ws = (char*)d_ws;
  float* A      = (float*)(ws);                         // 16777216 B
  float* thresh = (float*)(ws + 16777216);              // 128 B
  float* gmaxp  = (float*)(ws + 16777344);              // 128 B
  int*   kidx   = (int*)  (ws + 16777472);              // 1048576 B
  float* kval   = (float*)(ws + 17826048);              // 1048576 B
  float* LE     = (float*)(ws + 18874624);              // 33554432 B
  float* QKV    = (float*)(ws + 52429056);              // 100663296 B
  float* ctx    = (float*)(ws + 153092352);             // 32768 B

  hipMemsetAsync(out_sw, 0, (size_t)4194304 * 4, stream);
  hipMemsetAsync(ctx, 0, (size_t)BB * DD * 4, stream);

  conv_relu_kernel<<<BB * C1, 256, 0, stream>>>(x, conv_w, A);
  select_thresh_kernel<<<BB, 1024, 0, stream>>>(A, thresh, gmaxp);
  topk_pixel_kernel<<<BB * 4, 256, 0, stream>>>(A, thresh, gmaxp, out_sw, out_topi, kidx, kval);
  loc_emb_kernel<<<BB * SS, 256, 0, stream>>>(kidx, kval, emb, LE);
  qkv_gemm_kernel<<<dim3((BB * SS) / 64, TRIPLE / 64), 256, 0, stream>>>(LE, ipw, ipb, QKV);
  attn_kernel<<<BB * NHH * 4, 256, 0, stream>>>(QKV, ctx);
  pooled_kernel<<<BB, 256, 0, stream>>>(ctx, opw, opb, out_pooled);
}

// Round 2
// 699.473 us; speedup vs baseline: 2.3297x; 2.3297x over previous
//
#include <hip/hip_runtime.h>
#include <hip/hip_bf16.h>

// Problem constants
#define BB 32
#define C1 128
#define HH 32
#define WW 32
#define SS 1024        // H*W
#define DD 256
#define NHH 8
#define DHH 32
#define KSEL 66        // ceil(0.0005*128*32*32)
#define TRIPLE 768

typedef __attribute__((ext_vector_type(8))) short bf16x8;
typedef __attribute__((ext_vector_type(4))) float f32x4;

__device__ inline short f2bf(float f) {
  union { float f; unsigned u; } x; x.f = f;
  unsigned r = (x.u + 0x7FFFu + ((x.u >> 16) & 1u)) >> 16;
  return (short)r;
}

// ---------------------------------------------------------------------------
// Kernel 1: 9x9 conv (cross-correlation, pad 4) + ReLU.  A: (B, C1, 32, 32)
// ---------------------------------------------------------------------------
__global__ __launch_bounds__(256) void conv_relu_kernel(
    const float* __restrict__ x, const float* __restrict__ w, float* __restrict__ A) {
  const int bx = blockIdx.x;              // b*128 + c
  const int b = bx >> 7, c = bx & 127;
  __shared__ float xs[40 * 40];
  __shared__ float ws[81];
  const int t = threadIdx.x;
  for (int i = t; i < 1600; i += 256) {
    int r = i / 40, cc = i - r * 40;
    int gi = r - 4, gj = cc - 4;
    float v = 0.f;
    if (gi >= 0 && gi < 32 && gj >= 0 && gj < 32) v = x[(size_t)b * 1024 + gi * 32 + gj];
    xs[i] = v;
  }
  if (t < 81) ws[t] = w[(size_t)c * 81 + t];
  __syncthreads();
#pragma unroll
  for (int i = 0; i < 4; ++i) {
    int p = t + i * 256;
    int r = p >> 5, col = p & 31;
    float acc = 0.f;
#pragma unroll
    for (int u = 0; u < 9; ++u)
#pragma unroll
      for (int v = 0; v < 9; ++v)
        acc += xs[(r + u) * 40 + col + v] * ws[u * 9 + v];
    A[(size_t)bx * 1024 + p] = fmaxf(acc, 0.f);
  }
}

// ---------------------------------------------------------------------------
// Kernel 2: exact 66th-largest per batch via 3-level radix select on float
// bits (values are >= 0 so uint ordering == float ordering). Also global max.
// ---------------------------------------------------------------------------
__global__ __launch_bounds__(1024) void select_thresh_kernel(
    const float* __restrict__ A, float* __restrict__ thresh, float* __restrict__ gmaxp) {
  const int b = blockIdx.x;
  const float* Ab = A + (size_t)b * (C1 * SS);
  __shared__ unsigned hist[2048];
  __shared__ unsigned s_sel, s_rank, s_gbits;
  const int tid = threadIdx.x;
  if (tid == 0) s_gbits = 0u;
  for (int i = tid; i < 2048; i += 1024) hist[i] = 0u;
  __syncthreads();
  unsigned lmax = 0u;
  for (int i = tid; i < C1 * SS; i += 1024) {
    unsigned bits = __float_as_uint(Ab[i]);
    if (bits > lmax) lmax = bits;
    atomicAdd(&hist[bits >> 21], 1u);
  }
  atomicMax(&s_gbits, lmax);
  __syncthreads();
  if (tid == 0) {
    unsigned r = KSEL, cum = 0u;
    int bin = 2048;
    while (bin > 0) { --bin; cum += hist[bin]; if (cum >= r) break; }
    s_sel = (unsigned)bin;
    s_rank = r - (cum - hist[bin]);
  }
  __syncthreads();
  const unsigned v1 = s_sel;
  for (int i = tid; i < 2048; i += 1024) hist[i] = 0u;
  __syncthreads();
  for (int i = tid; i < C1 * SS; i += 1024) {
    unsigned bits = __float_as_uint(Ab[i]);
    if ((bits >> 21) == v1) atomicAdd(&hist[(bits >> 10) & 0x7FFu], 1u);
  }
  __syncthreads();
  if (tid == 0) {
    unsigned r = s_rank, cum = 0u;
    int bin = 2048;
    while (bin > 0) { --bin; cum += hist[bin]; if (cum >= r) break; }
    s_sel = (unsigned)bin;
    s_rank = r - (cum - hist[bin]);
  }
  __syncthreads();
  const unsigned v2 = s_sel;
  const unsigned pref = (v1 << 11) | v2;
  for (int i = tid; i < 1024; i += 1024) hist[i] = 0u;
  __syncthreads();
  for (int i = tid; i < C1 * SS; i += 1024) {
    unsigned bits = __float_as_uint(Ab[i]);
    if ((bits >> 10) == pref) atomicAdd(&hist[bits & 0x3FFu], 1u);
  }
  __syncthreads();
  if (tid == 0) {
    unsigned r = s_rank, cum = 0u;
    int bin = 1024;
    while (bin > 0) { --bin; cum += hist[bin]; if (cum >= r) break; }
    unsigned tb = (v1 << 21) | (v2 << 10) | (unsigned)bin;
    thresh[b] = __uint_as_float(tb);
    gmaxp[b] = __uint_as_float(s_gbits);
  }
}

// ---------------------------------------------------------------------------
// Kernel 3: per-pixel masked channel top-8 (jax tie-break: desc value, ties ->
// lower index; zero slots fill with smallest unused channel indices).
// ---------------------------------------------------------------------------
__global__ __launch_bounds__(256) void topk_pixel_kernel(
    const float* __restrict__ A, const float* __restrict__ thresh,
    const float* __restrict__ gmaxp, float* __restrict__ out_sw,
    float* __restrict__ out_topi, int* __restrict__ kidx, float* __restrict__ kval) {
  const int bx = blockIdx.x;              // b*4 + chunk
  const int b = bx >> 2;
  const int p = ((bx & 3) << 8) + threadIdx.x;
  const float th = thresh[b];
  const float gm = gmaxp[b];
  const float scale = gm > 0.f ? 1.f / gm : 0.f;
  const float* Ab = A + (size_t)b * (C1 * SS) + p;

  float tv0 = -1.f, tv1 = -1.f, tv2 = -1.f, tv3 = -1.f, tv4 = -1.f, tv5 = -1.f, tv6 = -1.f, tv7 = -1.f;
  int ti0 = 0, ti1 = 0, ti2 = 0, ti3 = 0, ti4 = 0, ti5 = 0, ti6 = 0, ti7 = 0;
  int cnt = 0;
#pragma unroll 1
  for (int c = 0; c < C1; ++c) {
    float v = Ab[(size_t)c << 10];
    if (v >= th) {
      ++cnt;
      bool s7 = v > tv6, p7 = (v > tv7) && !s7;
      float n7 = p7 ? v : (s7 ? tv6 : tv7); int m7 = p7 ? c : (s7 ? ti6 : ti7);
      bool s6 = v > tv5, p6 = (v > tv6) && !s6;
      float n6 = p6 ? v : (s6 ? tv5 : tv6); int m6 = p6 ? c : (s6 ? ti5 : ti6);
      bool s5 = v > tv4, p5 = (v > tv5) && !s5;
      float n5 = p5 ? v : (s5 ? tv4 : tv5); int m5 = p5 ? c : (s5 ? ti4 : ti5);
      bool s4 = v > tv3, p4 = (v > tv4) && !s4;
      float n4 = p4 ? v : (s4 ? tv3 : tv4); int m4 = p4 ? c : (s4 ? ti3 : ti4);
      bool s3 = v > tv2, p3 = (v > tv3) && !s3;
      float n3 = p3 ? v : (s3 ? tv2 : tv3); int m3 = p3 ? c : (s3 ? ti2 : ti3);
      bool s2 = v > tv1, p2 = (v > tv2) && !s2;
      float n2 = p2 ? v : (s2 ? tv1 : tv2); int m2 = p2 ? c : (s2 ? ti1 : ti2);
      bool s1 = v > tv0, p1 = (v > tv1) && !s1;
      float n1 = p1 ? v : (s1 ? tv0 : tv1); int m1 = p1 ? c : (s1 ? ti0 : ti1);
      bool p0 = v > tv0;
      float n0 = p0 ? v : tv0; int m0 = p0 ? c : ti0;
      tv7 = n7; ti7 = m7; tv6 = n6; ti6 = m6; tv5 = n5; ti5 = m5; tv4 = n4; ti4 = m4;
      tv3 = n3; ti3 = m3; tv2 = n2; ti2 = m2; tv1 = n1; ti1 = m1; tv0 = n0; ti0 = m0;
    }
  }
  const int m = cnt < 8 ? cnt : 8;
  int fv[8] = {ti0, ti1, ti2, ti3, ti4, ti5, ti6, ti7};
  int fill_c = 0;
#pragma unroll
  for (int j = 0; j < 8; ++j) {
    if (j >= m) {
      bool adv = true;
      while (adv) {
        adv = false;
#pragma unroll
        for (int t2 = 0; t2 < 8; ++t2)
          if (t2 < m && fv[t2] == fill_c) adv = true;
        if (adv) ++fill_c;
      }
      fv[j] = fill_c;
      ++fill_c;
    }
  }
  ti0 = fv[0]; ti1 = fv[1]; ti2 = fv[2]; ti3 = fv[3]; ti4 = fv[4]; ti5 = fv[5]; ti6 = fv[6]; ti7 = fv[7];
  if (m <= 0) tv0 = 0.f; if (m <= 1) tv1 = 0.f; if (m <= 2) tv2 = 0.f; if (m <= 3) tv3 = 0.f;
  if (m <= 4) tv4 = 0.f; if (m <= 5) tv5 = 0.f; if (m <= 6) tv6 = 0.f; if (m <= 7) tv7 = 0.f;

  const size_t pix = (size_t)b * SS + p;
  float* tp = out_topi + pix * 8;
  tp[0] = (float)ti0; tp[1] = (float)ti1; tp[2] = (float)ti2; tp[3] = (float)ti3;
  tp[4] = (float)ti4; tp[5] = (float)ti5; tp[6] = (float)ti6; tp[7] = (float)ti7;
  int* ki = kidx + pix * 8;
  ki[0] = ti0; ki[1] = ti1; ki[2] = ti2; ki[3] = ti3; ki[4] = ti4; ki[5] = ti5; ki[6] = ti6; ki[7] = ti7;
  float* kv = kval + pix * 8;
  float sv0 = tv0 * scale, sv1 = tv1 * scale, sv2 = tv2 * scale, sv3 = tv3 * scale;
  float sv4 = tv4 * scale, sv5 = tv5 * scale, sv6 = tv6 * scale, sv7 = tv7 * scale;
  kv[0] = sv0; kv[1] = sv1; kv[2] = sv2; kv[3] = sv3; kv[4] = sv4; kv[5] = sv5; kv[6] = sv6; kv[7] = sv7;
  float* sw = out_sw + pix * C1;
  if (m > 0) sw[ti0] = sv0; if (m > 1) sw[ti1] = sv1; if (m > 2) sw[ti2] = sv2; if (m > 3) sw[ti3] = sv3;
  if (m > 4) sw[ti4] = sv4; if (m > 5) sw[ti5] = sv5; if (m > 6) sw[ti6] = sv6; if (m > 7) sw[ti7] = sv7;
}

// ---------------------------------------------------------------------------
// Kernel 4: loc_emb(b,p,d) = PE(w,d) + sum_j kval[j]*emb[kidx[j], d]
// ---------------------------------------------------------------------------
__global__ __launch_bounds__(256) void loc_emb_kernel(
    const int* __restrict__ kidx, const float* __restrict__ kval,
    const float* __restrict__ emb, float* __restrict__ le) {
  const int pix = blockIdx.x;             // b*1024 + p
  const int d = threadIdx.x;
  const int w = pix & 31;
  const int i2 = d >> 1;
  const float div = expf((float)(2 * i2) * (-9.210340371976184f / 256.f));
  const float ang = (float)w * div;
  const float pe = (d & 1) ? cosf(ang) : sinf(ang);
  const int* ki = kidx + (size_t)pix * 8;
  const float* kv = kval + (size_t)pix * 8;
  float acc = pe;
#pragma unroll
  for (int j = 0; j < 8; ++j) acc += kv[j] * emb[(size_t)ki[j] * DD + d];
  le[(size_t)pix * DD + d] = acc;
}

// ---------------------------------------------------------------------------
// Kernel 5: QKV = LE(32768x256) @ in_proj_w^T(256x768) + b.  bf16 MFMA GEMM.
// 128x128 tile, 2x2 waves of 64x64, K-step 32.
// ---------------------------------------------------------------------------
__global__ __launch_bounds__(256) void qkv_mfma_kernel(
    const float* __restrict__ X, const float* __restrict__ W,
    const float* __restrict__ bias, float* __restrict__ Y) {
  __shared__ __align__(16) short As[128][40];
  __shared__ __align__(16) short Bs[128][40];
  const int bid = blockIdx.x;                 // 1536 blocks = 8 * 192
  const int wgid = (bid & 7) * 192 + (bid >> 3);
  const int nt = wgid % 6, mt = wgid / 6;
  const int t = threadIdx.x;
  const int wv = t >> 6, lane = t & 63, lg = lane >> 4, ln = lane & 15;
  const int wm = wv >> 1, wn = wv & 1;

  f32x4 acc[4][4];
#pragma unroll
  for (int i = 0; i < 4; ++i)
#pragma unroll
    for (int j = 0; j < 4; ++j) acc[i][j] = (f32x4){0, 0, 0, 0};

  for (int k0 = 0; k0 < DD; k0 += 32) {
    __syncthreads();
    for (int f = t; f < 1024; f += 256) {
      int row = f >> 3, q4 = (f & 7) * 4;
      float4 xa = *(const float4*)&X[(size_t)(mt * 128 + row) * DD + k0 + q4];
      float4 wa = *(const float4*)&W[(size_t)(nt * 128 + row) * DD + k0 + q4];
      short* ad = &As[row][q4];
      ad[0] = f2bf(xa.x); ad[1] = f2bf(xa.y); ad[2] = f2bf(xa.z); ad[3] = f2bf(xa.w);
      short* bd = &Bs[row][q4];
      bd[0] = f2bf(wa.x); bd[1] = f2bf(wa.y); bd[2] = f2bf(wa.z); bd[3] = f2bf(wa.w);
    }
    __syncthreads();
    bf16x8 af[4], bfr[4];
#pragma unroll
    for (int i = 0; i < 4; ++i) af[i] = *(const bf16x8*)&As[wm * 64 + i * 16 + ln][lg * 8];
#pragma unroll
    for (int j = 0; j < 4; ++j) bfr[j] = *(const bf16x8*)&Bs[wn * 64 + j * 16 + ln][lg * 8];
#pragma unroll
    for (int i = 0; i < 4; ++i)
#pragma unroll
      for (int j = 0; j < 4; ++j)
        acc[i][j] = __builtin_amdgcn_mfma_f32_16x16x32_bf16(af[i], bfr[j], acc[i][j], 0, 0, 0);
  }
#pragma unroll
  for (int i = 0; i < 4; ++i) {
#pragma unroll
    for (int j = 0; j < 4; ++j) {
      int col = nt * 128 + wn * 64 + j * 16 + ln;
      float bcol = bias[col];
#pragma unroll
      for (int r = 0; r < 4; ++r) {
        int row = mt * 128 + wm * 64 + i * 16 + lg * 4 + r;
        Y[(size_t)row * TRIPLE + col] = acc[i][j][r] + bcol;
      }
    }
  }
}

// ---------------------------------------------------------------------------
// Kernel 6: bf16 MFMA flash attention; accumulates sum over q of ctx rows
// into ctx_sum (B, 256).  Block = (b, h, 64-q-row chunk); 4 waves x 16 rows.
// ---------------------------------------------------------------------------
__global__ __launch_bounds__(256) void attn_mfma_kernel(
    const float* __restrict__ QKV, float* __restrict__ ctx_sum) {
  const int bid = blockIdx.x;                 // 4096 blocks = 8 * 512
  const int wgid = (bid & 7) * 512 + (bid >> 3);
  const int qc = wgid & 15;
  const int h = (wgid >> 4) & 7;
  const int b = wgid >> 7;
  const int t = threadIdx.x;
  const int wv = t >> 6, lane = t & 63, lg = lane >> 4, ln = lane & 15;

  __shared__ __align__(16) short Ks[64][40];   // K tile [key][dh], 2-way pad
  __shared__ __align__(16) short Vt[32][72];   // V tile transposed [dh][key]
  __shared__ __align__(16) short Ps[4][16][72];// P per wave [qrow][key]

  const size_t baseB = (size_t)b * SS * TRIPLE;
  // Q fragment (A-layout): row = ln (q), k = lg*8+j (dh)
  const float* qp = QKV + baseB + (size_t)(qc * 64 + wv * 16 + ln) * TRIPLE + h * DHH + lg * 8;
  bf16x8 qf;
  {
    float4 a = *(const float4*)qp;
    float4 c = *(const float4*)(qp + 4);
    qf[0] = f2bf(a.x); qf[1] = f2bf(a.y); qf[2] = f2bf(a.z); qf[3] = f2bf(a.w);
    qf[4] = f2bf(c.x); qf[5] = f2bf(c.y); qf[6] = f2bf(c.z); qf[7] = f2bf(c.w);
  }
  float m[4] = {-1e30f, -1e30f, -1e30f, -1e30f};
  float lsum[4] = {0.f, 0.f, 0.f, 0.f};
  f32x4 acc[2] = {{0, 0, 0, 0}, {0, 0, 0, 0}};
  const float scale = 0.17677669529663687f;   // 1/sqrt(32)

  for (int tile = 0; tile < 16; ++tile) {
    __syncthreads();
    // stage K[64][32] and V^T[32][64] as bf16
    for (int f = t; f < 512; f += 256) {
      int key = f >> 3, d0 = (f & 7) * 4;
      const float* kp = QKV + baseB + (size_t)(tile * 64 + key) * TRIPLE + DD + h * DHH + d0;
      float4 kv4 = *(const float4*)kp;
      float4 vv4 = *(const float4*)(kp + DD);
      short* kd = &Ks[key][d0];
      kd[0] = f2bf(kv4.x); kd[1] = f2bf(kv4.y); kd[2] = f2bf(kv4.z); kd[3] = f2bf(kv4.w);
      Vt[d0 + 0][key] = f2bf(vv4.x); Vt[d0 + 1][key] = f2bf(vv4.y);
      Vt[d0 + 2][key] = f2bf(vv4.z); Vt[d0 + 3][key] = f2bf(vv4.w);
    }
    __syncthreads();
    // QK^T: S[16 q][64 key], 4 key-subtiles
    f32x4 s[4];
#pragma unroll
    for (int st = 0; st < 4; ++st) {
      bf16x8 kf = *(const bf16x8*)&Ks[st * 16 + ln][lg * 8];
      s[st] = __builtin_amdgcn_mfma_f32_16x16x32_bf16(qf, kf, (f32x4){0, 0, 0, 0}, 0, 0, 0);
    }
    // online softmax per q-row (row = lg*4 + r)
    float corr[4];
#pragma unroll
    for (int r = 0; r < 4; ++r) {
      float mx = fmaxf(fmaxf(s[0][r], s[1][r]), fmaxf(s[2][r], s[3][r]));
      mx = fmaxf(mx, __shfl_xor(mx, 1));
      mx = fmaxf(mx, __shfl_xor(mx, 2));
      mx = fmaxf(mx, __shfl_xor(mx, 4));
      mx = fmaxf(mx, __shfl_xor(mx, 8));
      mx *= scale;
      float mn = fmaxf(m[r], mx);
      corr[r] = __expf(m[r] - mn);
      m[r] = mn;
      float ps = 0.f;
#pragma unroll
      for (int st = 0; st < 4; ++st) {
        float p = __expf(s[st][r] * scale - mn);
        s[st][r] = p;
        ps += p;
      }
      ps += __shfl_xor(ps, 1);
      ps += __shfl_xor(ps, 2);
      ps += __shfl_xor(ps, 4);
      ps += __shfl_xor(ps, 8);
      lsum[r] = lsum[r] * corr[r] + ps;
    }
    // P -> LDS (bf16), row = q (lg*4+r), col = key (st*16+ln)
#pragma unroll
    for (int st = 0; st < 4; ++st)
#pragma unroll
      for (int r = 0; r < 4; ++r)
        Ps[wv][lg * 4 + r][st * 16 + ln] = f2bf(s[st][r]);
    // rescale O accumulators
#pragma unroll
    for (int sb = 0; sb < 2; ++sb)
#pragma unroll
      for (int r = 0; r < 4; ++r)
        acc[sb][r] *= corr[r];
    __syncthreads();
    // PV: O[16 q][32 d] += P[16 q][64 k] * V[64 k][32 d]
#pragma unroll
    for (int ks = 0; ks < 2; ++ks) {
      bf16x8 pa = *(const bf16x8*)&Ps[wv][ln][ks * 32 + lg * 8];
#pragma unroll
      for (int sb = 0; sb < 2; ++sb) {
        bf16x8 vb = *(const bf16x8*)&Vt[sb * 16 + ln][ks * 32 + lg * 8];
        acc[sb] = __builtin_amdgcn_mfma_f32_16x16x32_bf16(pa, vb, acc[sb], 0, 0, 0);
      }
    }
  }
  // normalize rows, reduce over 16 q-rows of this wave, atomically add
  float invl[4];
#pragma unroll
  for (int r = 0; r < 4; ++r) invl[r] = 1.f / lsum[r];
#pragma unroll
  for (int sb = 0; sb < 2; ++sb) {
    float v = acc[sb][0] * invl[0] + acc[sb][1] * invl[1] +
              acc[sb][2] * invl[2] + acc[sb][3] * invl[3];
    v += __shfl_xor(v, 16);
    v += __shfl_xor(v, 32);
    if (lg == 0) atomicAdd(&ctx_sum[b * DD + h * DHH + sb * 16 + ln], v);
  }
}

// ---------------------------------------------------------------------------
// Kernel 7: pooled(b,o) = bias[o] + sum_d (ctx_sum[b,d]/1024) * Wout[o,d]
// ---------------------------------------------------------------------------
__global__ __launch_bounds__(256) void pooled_kernel(
    const float* __restrict__ ctx_sum, const float* __restrict__ Wout,
    const float* __restrict__ bout, float* __restrict__ out) {
  const int b = blockIdx.x;
  const int o = threadIdx.x;
  __shared__ float mc[DD];
  mc[o] = ctx_sum[b * DD + o] * (1.f / 1024.f);
  __syncthreads();
  float acc = bout[o];
  const float* wr = Wout + (size_t)o * DD;
#pragma unroll 4
  for (int d = 0; d < DD; ++d) acc += mc[d] * wr[d];
  out[b * DD + o] = acc;
}

// ---------------------------------------------------------------------------
extern "C" void kernel_launch(void* const* d_in, const int* in_sizes, int n_in,
                              void* d_out, int out_size, void* d_ws, size_t ws_size,
                              hipStream_t stream) {
  const float* x = (const float*)d_in[0];
  const float* conv_w = (const float*)d_in[1];
  const float* emb = (const float*)d_in[2];
  const float* ipw = (const float*)d_in[3];
  const float* ipb = (const float*)d_in[4];
  const float* opw = (const float*)d_in[5];
  const float* opb = (const float*)d_in[6];

  float* out = (float*)d_out;
  float* out_pooled = out;                          // 32*256      = 8192
  float* out_sw = out + 8192;                       // 32*32*32*128 = 4194304
  float* out_topi = out + 8192 + 4194304;           // 32*32*32*8  = 262144

  // workspace layout (total ~146 MiB)
  char* ws = (char*)d_ws;
  float* A      = (float*)(ws);                         // 16777216 B
  float* thresh = (float*)(ws + 16777216);              // 128 B
  float* gmaxp  = (float*)(ws + 16777344);              // 128 B
  int*   kidx   = (int*)  (ws + 16777472);              // 1048576 B
  float* kval   = (float*)(ws + 17826048);              // 1048576 B
  float* LE     = (float*)(ws + 18874624);              // 33554432 B
  float* QKV    = (float*)(ws + 52429056);              // 100663296 B
  float* ctx    = (float*)(ws + 153092352);             // 32768 B

  hipMemsetAsync(out_sw, 0, (size_t)4194304 * 4, stream);
  hipMemsetAsync(ctx, 0, (size_t)BB * DD * 4, stream);

  conv_relu_kernel<<<BB * C1, 256, 0, stream>>>(x, conv_w, A);
  select_thresh_kernel<<<BB, 1024, 0, stream>>>(A, thresh, gmaxp);
  topk_pixel_kernel<<<BB * 4, 256, 0, stream>>>(A, thresh, gmaxp, out_sw, out_topi, kidx, kval);
  loc_emb_kernel<<<BB * SS, 256, 0, stream>>>(kidx, kval, emb, LE);
  qkv_mfma_kernel<<<(BB * SS / 128) * (TRIPLE / 128), 256, 0, stream>>>(LE, ipw, ipb, QKV);
  attn_mfma_kernel<<<BB * NHH * (SS / 64), 256, 0, stream>>>(QKV, ctx);
  pooled_kernel<<<BB, 256, 0, stream>>>(ctx, opw, opb, out_pooled);
}

// Round 3
// 323.220 us; speedup vs baseline: 5.0418x; 2.1641x over previous
//
#include <hip/hip_runtime.h>
#include <hip/hip_bf16.h>

// Problem constants
#define BB 32
#define C1 128
#define SS 1024        // H*W
#define DD 256
#define NHH 8
#define DHH 32
#define KSEL 66        // ceil(0.0005*128*32*32)
#define TRIPLE 768
#define SELFLAG 0x40000000u

typedef __attribute__((ext_vector_type(8))) short bf16x8;
typedef __attribute__((ext_vector_type(4))) float f32x4;

__device__ inline short f2bf(float f) {
  union { __hip_bfloat16 h; unsigned short u; } c;
  c.h = __float2bfloat16(f);
  return (short)c.u;
}
__device__ inline float bf2f(short s) {
  union { float f; unsigned u; } c;
  c.u = ((unsigned)(unsigned short)s) << 16;
  return c.f;
}

// ---------------------------------------------------------------------------
// Kernel 1: 9x9 conv (cross-correlation, pad 4) + ReLU + fused level-1
// radix histogram (top 11 bits, zeros skipped) + per-batch max.
// ---------------------------------------------------------------------------
__global__ __launch_bounds__(256) void conv_relu_hist_kernel(
    const float* __restrict__ x, const float* __restrict__ w, float* __restrict__ A,
    unsigned* __restrict__ ghist1, unsigned* __restrict__ gmaxb) {
  const int bx = blockIdx.x;              // b*128 + c
  const int b = bx >> 7, c = bx & 127;
  __shared__ float xs[40 * 40];
  __shared__ float ws[81];
  __shared__ unsigned h[2048];
  __shared__ unsigned smax;
  const int t = threadIdx.x;
  for (int i = t; i < 1600; i += 256) {
    int r = i / 40, cc = i - r * 40;
    int gi = r - 4, gj = cc - 4;
    float v = 0.f;
    if (gi >= 0 && gi < 32 && gj >= 0 && gj < 32) v = x[(size_t)b * 1024 + gi * 32 + gj];
    xs[i] = v;
  }
  if (t < 81) ws[t] = w[(size_t)c * 81 + t];
  for (int i = t; i < 2048; i += 256) h[i] = 0u;
  if (t == 0) smax = 0u;
  __syncthreads();
  unsigned lmax = 0u;
#pragma unroll
  for (int i = 0; i < 4; ++i) {
    int p = t + i * 256;
    int r = p >> 5, col = p & 31;
    float acc = 0.f;
#pragma unroll
    for (int u = 0; u < 9; ++u)
#pragma unroll
      for (int v = 0; v < 9; ++v)
        acc += xs[(r + u) * 40 + col + v] * ws[u * 9 + v];
    acc = fmaxf(acc, 0.f);
    A[(size_t)bx * 1024 + p] = acc;
    unsigned bits = __float_as_uint(acc);
    if (bits > lmax) lmax = bits;
    if (bits >= (1u << 21)) atomicAdd(&h[bits >> 21], 1u);
  }
  atomicMax(&smax, lmax);
  __syncthreads();
  for (int i = t; i < 2048; i += 256)
    if (h[i]) atomicAdd(&ghist1[b * 2048 + i], h[i]);
  if (t == 0) atomicMax(&gmaxb[b], smax);
}

// ---------------------------------------------------------------------------
// Kernel 2a/2b: level-2 / level-3 radix histograms (rare-match passes)
// ---------------------------------------------------------------------------
__global__ __launch_bounds__(256) void hist2_kernel(
    const float* __restrict__ A, const unsigned* __restrict__ selv,
    unsigned* __restrict__ gh) {
  const int b = blockIdx.y, slice = blockIdx.x, t = threadIdx.x;
  const unsigned v1 = selv[b];
  __shared__ unsigned h[2048];
  for (int i = t; i < 2048; i += 256) h[i] = 0u;
  __syncthreads();
  const float* Ab = A + (size_t)b * (C1 * SS) + slice * 8192;
#pragma unroll 4
  for (int k = 0; k < 32; ++k) {
    unsigned bits = __float_as_uint(Ab[t + k * 256]);
    if ((bits >> 21) == v1) atomicAdd(&h[(bits >> 10) & 0x7FFu], 1u);
  }
  __syncthreads();
  for (int i = t; i < 2048; i += 256)
    if (h[i]) atomicAdd(&gh[b * 2048 + i], h[i]);
}

__global__ __launch_bounds__(256) void hist3_kernel(
    const float* __restrict__ A, const unsigned* __restrict__ selv,
    unsigned* __restrict__ gh) {
  const int b = blockIdx.y, slice = blockIdx.x, t = threadIdx.x;
  const unsigned pref = selv[b];
  __shared__ unsigned h[1024];
  for (int i = t; i < 1024; i += 256) h[i] = 0u;
  __syncthreads();
  const float* Ab = A + (size_t)b * (C1 * SS) + slice * 8192;
#pragma unroll 4
  for (int k = 0; k < 32; ++k) {
    unsigned bits = __float_as_uint(Ab[t + k * 256]);
    if ((bits >> 10) == pref) atomicAdd(&h[bits & 0x3FFu], 1u);
  }
  __syncthreads();
  for (int i = t; i < 1024; i += 256)
    if (h[i]) atomicAdd(&gh[b * 1024 + i], h[i]);
}

// ---------------------------------------------------------------------------
// Kernel 3: radix-level selection via parallel suffix scan. One block / batch.
// stage 0/1: nbins=2048 (pair-compressed), stage 2: nbins=1024 -> thresh.
// ---------------------------------------------------------------------------
__global__ __launch_bounds__(1024) void sel_kernel(
    const unsigned* __restrict__ gh, unsigned* __restrict__ selv,
    unsigned* __restrict__ selr, float* __restrict__ thresh,
    int nbins, int stage) {
  const int b = blockIdx.x, t = threadIdx.x;
  __shared__ unsigned hl[2048];
  __shared__ unsigned sfx[1024];
  unsigned r = (stage == 0) ? (unsigned)KSEL : selr[b];
  unsigned vold = (stage == 0) ? 0u : selv[b];
  if (nbins == 2048) {
    hl[t] = gh[b * 2048 + t];
    hl[t + 1024] = gh[b * 2048 + t + 1024];
  } else {
    hl[t] = gh[b * 1024 + t];
  }
  __syncthreads();
  sfx[t] = (nbins == 2048) ? (hl[2 * t] + hl[2 * t + 1]) : hl[t];
  __syncthreads();
  for (int off = 1; off < 1024; off <<= 1) {
    unsigned v = (t + off < 1024) ? sfx[t + off] : 0u;
    __syncthreads();
    sfx[t] += v;
    __syncthreads();
  }
  if ((stage != 0 && vold == SELFLAG) || sfx[0] < r) {
    if (t == 0) {
      if (stage == 2) thresh[b] = 0.0f;
      else { selv[b] = SELFLAG; selr[b] = r; }
    }
    return;
  }
  unsigned Snext = (t < 1023) ? sfx[t + 1] : 0u;
  if (nbins == 2048) {
    unsigned hi = hl[2 * t + 1], lo = hl[2 * t];
    if (Snext < r && Snext + hi >= r) {
      selv[b] = (vold << 11) | (unsigned)(2 * t + 1);
      selr[b] = r - Snext;
    } else if (Snext + hi < r && Snext + hi + lo >= r) {
      selv[b] = (vold << 11) | (unsigned)(2 * t);
      selr[b] = r - Snext - hi;
    }
  } else {
    if (Snext < r && sfx[t] >= r)
      thresh[b] = __uint_as_float((vold << 10) | (unsigned)t);
  }
}

// ---------------------------------------------------------------------------
// Kernel 4: per-pixel masked channel top-8 (jax tie-break semantics).
// ---------------------------------------------------------------------------
__global__ __launch_bounds__(256) void topk_pixel_kernel(
    const float* __restrict__ A, const float* __restrict__ thresh,
    const float* __restrict__ gmaxp, float* __restrict__ out_sw,
    float* __restrict__ out_topi, int* __restrict__ kidx, float* __restrict__ kval) {
  const int bx = blockIdx.x;              // b*4 + chunk
  const int b = bx >> 2;
  const int p = ((bx & 3) << 8) + threadIdx.x;
  const float th = thresh[b];
  const float gm = gmaxp[b];
  const float scale = gm > 0.f ? 1.f / gm : 0.f;
  const float* Ab = A + (size_t)b * (C1 * SS) + p;

  float tv0 = -1.f, tv1 = -1.f, tv2 = -1.f, tv3 = -1.f, tv4 = -1.f, tv5 = -1.f, tv6 = -1.f, tv7 = -1.f;
  int ti0 = 0, ti1 = 0, ti2 = 0, ti3 = 0, ti4 = 0, ti5 = 0, ti6 = 0, ti7 = 0;
  int cnt = 0;
#pragma unroll 1
  for (int c = 0; c < C1; ++c) {
    float v = Ab[(size_t)c << 10];
    if (v >= th) {
      ++cnt;
      bool s7 = v > tv6, p7 = (v > tv7) && !s7;
      float n7 = p7 ? v : (s7 ? tv6 : tv7); int m7 = p7 ? c : (s7 ? ti6 : ti7);
      bool s6 = v > tv5, p6 = (v > tv6) && !s6;
      float n6 = p6 ? v : (s6 ? tv5 : tv6); int m6 = p6 ? c : (s6 ? ti5 : ti6);
      bool s5 = v > tv4, p5 = (v > tv5) && !s5;
      float n5 = p5 ? v : (s5 ? tv4 : tv5); int m5 = p5 ? c : (s5 ? ti4 : ti5);
      bool s4 = v > tv3, p4 = (v > tv4) && !s4;
      float n4 = p4 ? v : (s4 ? tv3 : tv4); int m4 = p4 ? c : (s4 ? ti3 : ti4);
      bool s3 = v > tv2, p3 = (v > tv3) && !s3;
      float n3 = p3 ? v : (s3 ? tv2 : tv3); int m3 = p3 ? c : (s3 ? ti2 : ti3);
      bool s2 = v > tv1, p2 = (v > tv2) && !s2;
      float n2 = p2 ? v : (s2 ? tv1 : tv2); int m2 = p2 ? c : (s2 ? ti1 : ti2);
      bool s1 = v > tv0, p1 = (v > tv1) && !s1;
      float n1 = p1 ? v : (s1 ? tv0 : tv1); int m1 = p1 ? c : (s1 ? ti0 : ti1);
      bool p0 = v > tv0;
      float n0 = p0 ? v : tv0; int m0 = p0 ? c : ti0;
      tv7 = n7; ti7 = m7; tv6 = n6; ti6 = m6; tv5 = n5; ti5 = m5; tv4 = n4; ti4 = m4;
      tv3 = n3; ti3 = m3; tv2 = n2; ti2 = m2; tv1 = n1; ti1 = m1; tv0 = n0; ti0 = m0;
    }
  }
  const int m = cnt < 8 ? cnt : 8;
  int fv[8] = {ti0, ti1, ti2, ti3, ti4, ti5, ti6, ti7};
  int fill_c = 0;
#pragma unroll
  for (int j = 0; j < 8; ++j) {
    if (j >= m) {
      bool adv = true;
      while (adv) {
        adv = false;
#pragma unroll
        for (int t2 = 0; t2 < 8; ++t2)
          if (t2 < m && fv[t2] == fill_c) adv = true;
        if (adv) ++fill_c;
      }
      fv[j] = fill_c;
      ++fill_c;
    }
  }
  ti0 = fv[0]; ti1 = fv[1]; ti2 = fv[2]; ti3 = fv[3]; ti4 = fv[4]; ti5 = fv[5]; ti6 = fv[6]; ti7 = fv[7];
  if (m <= 0) tv0 = 0.f; if (m <= 1) tv1 = 0.f; if (m <= 2) tv2 = 0.f; if (m <= 3) tv3 = 0.f;
  if (m <= 4) tv4 = 0.f; if (m <= 5) tv5 = 0.f; if (m <= 6) tv6 = 0.f; if (m <= 7) tv7 = 0.f;

  const size_t pix = (size_t)b * SS + p;
  float* tp = out_topi + pix * 8;
  tp[0] = (float)ti0; tp[1] = (float)ti1; tp[2] = (float)ti2; tp[3] = (float)ti3;
  tp[4] = (float)ti4; tp[5] = (float)ti5; tp[6] = (float)ti6; tp[7] = (float)ti7;
  int* ki = kidx + pix * 8;
  ki[0] = ti0; ki[1] = ti1; ki[2] = ti2; ki[3] = ti3; ki[4] = ti4; ki[5] = ti5; ki[6] = ti6; ki[7] = ti7;
  float* kv = kval + pix * 8;
  float sv0 = tv0 * scale, sv1 = tv1 * scale, sv2 = tv2 * scale, sv3 = tv3 * scale;
  float sv4 = tv4 * scale, sv5 = tv5 * scale, sv6 = tv6 * scale, sv7 = tv7 * scale;
  kv[0] = sv0; kv[1] = sv1; kv[2] = sv2; kv[3] = sv3; kv[4] = sv4; kv[5] = sv5; kv[6] = sv6; kv[7] = sv7;
  float* sw = out_sw + pix * C1;
  if (m > 0) sw[ti0] = sv0; if (m > 1) sw[ti1] = sv1; if (m > 2) sw[ti2] = sv2; if (m > 3) sw[ti3] = sv3;
  if (m > 4) sw[ti4] = sv4; if (m > 5) sw[ti5] = sv5; if (m > 6) sw[ti6] = sv6; if (m > 7) sw[ti7] = sv7;
}

// ---------------------------------------------------------------------------
// Kernel 5: loc_emb(b,p,d) = PE(w,d) + sum_j kval[j]*emb[kidx[j], d] -> bf16
// ---------------------------------------------------------------------------
__global__ __launch_bounds__(256) void loc_emb_kernel(
    const int* __restrict__ kidx, const float* __restrict__ kval,
    const float* __restrict__ emb, unsigned short* __restrict__ le) {
  const int pix = blockIdx.x;             // b*1024 + p
  const int d = threadIdx.x;
  const int w = pix & 31;
  const int i2 = d >> 1;
  const float div = expf((float)(2 * i2) * (-9.210340371976184f / 256.f));
  const float ang = (float)w * div;
  const float pe = (d & 1) ? cosf(ang) : sinf(ang);
  const int* ki = kidx + (size_t)pix * 8;
  const float* kv = kval + (size_t)pix * 8;
  float acc = pe;
#pragma unroll
  for (int j = 0; j < 8; ++j) acc += kv[j] * emb[(size_t)ki[j] * DD + d];
  le[(size_t)pix * DD + d] = (unsigned short)f2bf(acc);
}

// ---------------------------------------------------------------------------
// Kernel 5b: in_proj_w fp32 -> bf16
// ---------------------------------------------------------------------------
__global__ __launch_bounds__(256) void w2bf_kernel(
    const float* __restrict__ W, unsigned short* __restrict__ Wb) {
  int i = blockIdx.x * 256 + threadIdx.x;
  Wb[i] = (unsigned short)f2bf(W[i]);
}

// ---------------------------------------------------------------------------
// Kernel 6: QKV(bf16) = LE(32768x256 bf16) @ Wb^T(256x768 bf16) + bias.
// 128x128 tile, 2x2 waves of 64x64, K-step 32.
// ---------------------------------------------------------------------------
__global__ __launch_bounds__(256) void qkv_mfma_kernel(
    const unsigned short* __restrict__ Xb, const unsigned short* __restrict__ Wb,
    const float* __restrict__ bias, unsigned short* __restrict__ Yb) {
  __shared__ __align__(16) short As[128][40];
  __shared__ __align__(16) short Bs[128][40];
  const int bid = blockIdx.x;                 // 1536 blocks = 8 * 192
  const int wgid = (bid & 7) * 192 + (bid >> 3);
  const int nt = wgid % 6, mt = wgid / 6;
  const int t = threadIdx.x;
  const int wv = t >> 6, lane = t & 63, lg = lane >> 4, ln = lane & 15;
  const int wm = wv >> 1, wn = wv & 1;

  f32x4 acc[4][4];
#pragma unroll
  for (int i = 0; i < 4; ++i)
#pragma unroll
    for (int j = 0; j < 4; ++j) acc[i][j] = (f32x4){0, 0, 0, 0};

  for (int k0 = 0; k0 < DD; k0 += 32) {
    __syncthreads();
#pragma unroll
    for (int ii = 0; ii < 2; ++ii) {
      int f = t + ii * 256;
      int row = f >> 2, kg = (f & 3) * 8;
      *(bf16x8*)&As[row][kg] = *(const bf16x8*)&Xb[(size_t)(mt * 128 + row) * DD + k0 + kg];
      *(bf16x8*)&Bs[row][kg] = *(const bf16x8*)&Wb[(size_t)(nt * 128 + row) * DD + k0 + kg];
    }
    __syncthreads();
    bf16x8 af[4], bfr[4];
#pragma unroll
    for (int i = 0; i < 4; ++i) af[i] = *(const bf16x8*)&As[wm * 64 + i * 16 + ln][lg * 8];
#pragma unroll
    for (int j = 0; j < 4; ++j) bfr[j] = *(const bf16x8*)&Bs[wn * 64 + j * 16 + ln][lg * 8];
#pragma unroll
    for (int i = 0; i < 4; ++i)
#pragma unroll
      for (int j = 0; j < 4; ++j)
        acc[i][j] = __builtin_amdgcn_mfma_f32_16x16x32_bf16(af[i], bfr[j], acc[i][j], 0, 0, 0);
  }
#pragma unroll
  for (int i = 0; i < 4; ++i) {
#pragma unroll
    for (int j = 0; j < 4; ++j) {
      int col = nt * 128 + wn * 64 + j * 16 + ln;
      float bcol = bias[col];
#pragma unroll
      for (int r = 0; r < 4; ++r) {
        int row = mt * 128 + wm * 64 + i * 16 + lg * 4 + r;
        Yb[(size_t)row * TRIPLE + col] = (unsigned short)f2bf(acc[i][j][r] + bcol);
      }
    }
  }
}

// ---------------------------------------------------------------------------
// Kernel 7: bf16 MFMA flash attention, swapped QK^T (lane-local softmax);
// accumulates sum over q of normalized ctx rows into ctx_sum (B, 256).
// Block = (b, h, 64-q-row chunk); 4 waves x 16 q-rows.
// ---------------------------------------------------------------------------
__global__ __launch_bounds__(256) void attn_mfma_kernel(
    const unsigned short* __restrict__ QKV, float* __restrict__ ctx_sum) {
  const int bid = blockIdx.x;                 // 4096 blocks = 8 * 512
  const int wgid = (bid & 7) * 512 + (bid >> 3);
  const int qc = wgid & 15;
  const int h = (wgid >> 4) & 7;
  const int b = wgid >> 7;
  const int t = threadIdx.x;
  const int wv = t >> 6, lane = t & 63, lg = lane >> 4, ln = lane & 15;

  __shared__ __align__(16) short Ks[64][40];    // K tile [key][dh]
  __shared__ __align__(16) short Vt[32][72];    // V tile transposed [dh][key]
  __shared__ __align__(16) short Ps[4][16][72]; // P per wave [qrow][key]

  const size_t baseB = (size_t)b * SS * TRIPLE;
  const float scale = 0.17677669529663687f;     // 1/sqrt(32)
  // Q fragment (B-layout): col = ln (q), k = lg*8+j (dh); pre-scaled
  bf16x8 qf;
  {
    const unsigned short* qp = QKV + baseB + (size_t)(qc * 64 + wv * 16 + ln) * TRIPLE + h * DHH + lg * 8;
    bf16x8 qr = *(const bf16x8*)qp;
#pragma unroll
    for (int j = 0; j < 8; ++j) qf[j] = f2bf(bf2f(qr[j]) * scale);
  }
  float m = -1e30f, l = 0.f;                    // per-lane state for q = ln
  f32x4 acc[2] = {{0, 0, 0, 0}, {0, 0, 0, 0}};

  for (int tile = 0; tile < 16; ++tile) {
    __syncthreads();
    // stage K[64][32] and V^T[32][64] as bf16 (1 short8 each per thread)
    {
      int key = t >> 2, d0 = (t & 3) * 8;
      const unsigned short* kp = QKV + baseB + (size_t)(tile * 64 + key) * TRIPLE + DD + h * DHH + d0;
      bf16x8 kv8 = *(const bf16x8*)kp;
      bf16x8 vv8 = *(const bf16x8*)(kp + DD);
      *(bf16x8*)&Ks[key][d0] = kv8;
#pragma unroll
      for (int j = 0; j < 8; ++j) Vt[d0 + j][key] = vv8[j];
    }
    __syncthreads();
    // swapped QK^T: S^T[key][q]; lane ln = q, regs/lg hold 16 of 64 keys
    f32x4 s[4];
#pragma unroll
    for (int st = 0; st < 4; ++st) {
      bf16x8 kf = *(const bf16x8*)&Ks[st * 16 + ln][lg * 8];
      s[st] = __builtin_amdgcn_mfma_f32_16x16x32_bf16(kf, qf, (f32x4){0, 0, 0, 0}, 0, 0, 0);
    }
    // lane-local online softmax for q = ln
    float mx = s[0][0];
#pragma unroll
    for (int st = 0; st < 4; ++st)
#pragma unroll
      for (int r = 0; r < 4; ++r) mx = fmaxf(mx, s[st][r]);
    mx = fmaxf(mx, __shfl_xor(mx, 16));
    mx = fmaxf(mx, __shfl_xor(mx, 32));
    float mn = fmaxf(m, mx);
    float corr = __expf(m - mn);
    m = mn;
    float ps = 0.f;
#pragma unroll
    for (int st = 0; st < 4; ++st)
#pragma unroll
      for (int r = 0; r < 4; ++r) {
        float p = __expf(s[st][r] - mn);
        s[st][r] = p;
        ps += p;
      }
    ps += __shfl_xor(ps, 16);
    ps += __shfl_xor(ps, 32);
    l = l * corr + ps;
    // P -> LDS: Ps[q=ln][key = st*16 + lg*4 + r]
#pragma unroll
    for (int st = 0; st < 4; ++st)
#pragma unroll
      for (int r = 0; r < 4; ++r)
        Ps[wv][ln][st * 16 + lg * 4 + r] = f2bf(s[st][r]);
    // rescale O accumulator rows (row q = lg*4 + r -> corr from lane ln'=q)
    float corrq[4];
#pragma unroll
    for (int r = 0; r < 4; ++r)
      corrq[r] = __shfl(corr, (lane & 48) | (lg * 4 + r));
#pragma unroll
    for (int sb = 0; sb < 2; ++sb)
#pragma unroll
      for (int r = 0; r < 4; ++r)
        acc[sb][r] *= corrq[r];
    __syncthreads();
    // PV: O[16 q][32 d] += P[16 q][64 k] * V^T[32 d][64 k]
#pragma unroll
    for (int ks = 0; ks < 2; ++ks) {
      bf16x8 pa = *(const bf16x8*)&Ps[wv][ln][ks * 32 + lg * 8];
#pragma unroll
      for (int sb = 0; sb < 2; ++sb) {
        bf16x8 vb = *(const bf16x8*)&Vt[sb * 16 + ln][ks * 32 + lg * 8];
        acc[sb] = __builtin_amdgcn_mfma_f32_16x16x32_bf16(pa, vb, acc[sb], 0, 0, 0);
      }
    }
  }
  // normalize rows by 1/l(q), reduce over this wave's 16 q-rows, atomic add
  float invl = 1.f / l;
  float invq[4];
#pragma unroll
  for (int r = 0; r < 4; ++r)
    invq[r] = __shfl(invl, (lane & 48) | (lg * 4 + r));
#pragma unroll
  for (int sb = 0; sb < 2; ++sb) {
    float v = acc[sb][0] * invq[0] + acc[sb][1] * invq[1] +
              acc[sb][2] * invq[2] + acc[sb][3] * invq[3];
    v += __shfl_xor(v, 16);
    v += __shfl_xor(v, 32);
    if (lane < 16) atomicAdd(&ctx_sum[b * DD + h * DHH + sb * 16 + lane], v);
  }
}

// ---------------------------------------------------------------------------
// Kernel 8: pooled(b,o) = bias[o] + sum_d (ctx_sum[b,d]/1024) * Wout[o,d]
// ---------------------------------------------------------------------------
__global__ __launch_bounds__(256) void pooled_kernel(
    const float* __restrict__ ctx_sum, const float* __restrict__ Wout,
    const float* __restrict__ bout, float* __restrict__ out) {
  const int b = blockIdx.x;
  const int o = threadIdx.x;
  __shared__ float mc[DD];
  mc[o] = ctx_sum[b * DD + o] * (1.f / 1024.f);
  __syncthreads();
  float acc = bout[o];
  const float* wr = Wout + (size_t)o * DD;
#pragma unroll 4
  for (int d = 0; d < DD; ++d) acc += mc[d] * wr[d];
  out[b * DD + o] = acc;
}

// ---------------------------------------------------------------------------
extern "C" void kernel_launch(void* const* d_in, const int* in_sizes, int n_in,
                              void* d_out, int out_size, void* d_ws, size_t ws_size,
                              hipStream_t stream) {
  const float* x = (const float*)d_in[0];
  const float* conv_w = (const float*)d_in[1];
  const float* emb = (const float*)d_in[2];
  const float* ipw = (const float*)d_in[3];
  const float* ipb = (const float*)d_in[4];
  const float* opw = (const float*)d_in[5];
  const float* opb = (const float*)d_in[6];

  float* out = (float*)d_out;
  float* out_pooled = out;                          // 32*256       = 8192
  float* out_sw = out + 8192;                       // 32*32*32*128 = 4194304
  float* out_topi = out + 8192 + 4194304;           // 32*32*32*8   = 262144

  // workspace layout (~87 MiB)
  char* ws = (char*)d_ws;
  float*    A      = (float*)(ws);                      // 16777216 B
  unsigned* ghist1 = (unsigned*)(ws + 16777216);        // 262144 B
  unsigned* ghist2 = (unsigned*)(ws + 17039360);        // 262144 B
  unsigned* ghist3 = (unsigned*)(ws + 17301504);        // 131072 B
  unsigned* selv   = (unsigned*)(ws + 17432576);        // 128 B
  unsigned* selr   = (unsigned*)(ws + 17432704);        // 128 B
  float*    thresh = (float*)(ws + 17432832);           // 128 B
  unsigned* gmaxb  = (unsigned*)(ws + 17432960);        // 128 B
  int*      kidx   = (int*)(ws + 17433088);             // 1048576 B
  float*    kval   = (float*)(ws + 18481664);           // 1048576 B
  unsigned short* LE  = (unsigned short*)(ws + 19530240);   // 16777216 B
  unsigned short* QKV = (unsigned short*)(ws + 36307456);   // 50331648 B
  float*    ctx    = (float*)(ws + 86639104);           // 32768 B
  unsigned short* WB  = (unsigned short*)(ws + 86671872);   // 393216 B

  hipMemsetAsync(out_sw, 0, (size_t)4194304 * 4, stream);
  hipMemsetAsync(ws + 16777216, 0, 655872, stream);     // hists + sel + gmax
  hipMemsetAsync(ctx, 0, (size_t)BB * DD * 4, stream);

  conv_relu_hist_kernel<<<BB * C1, 256, 0, stream>>>(x, conv_w, A, ghist1, gmaxb);
  sel_kernel<<<BB, 1024, 0, stream>>>(ghist1, selv, selr, thresh, 2048, 0);
  hist2_kernel<<<dim3(16, BB), 256, 0, stream>>>(A, selv, ghist2);
  sel_kernel<<<BB, 1024, 0, stream>>>(ghist2, selv, selr, thresh, 2048, 1);
  hist3_kernel<<<dim3(16, BB), 256, 0, stream>>>(A, selv, ghist3);
  sel_kernel<<<BB, 1024, 0, stream>>>(ghist3, selv, selr, thresh, 1024, 2);
  topk_pixel_kernel<<<BB * 4, 256, 0, stream>>>(A, thresh, (const float*)gmaxb, out_sw, out_topi, kidx, kval);
  loc_emb_kernel<<<BB * SS, 256, 0, stream>>>(kidx, kval, emb, LE);
  w2bf_kernel<<<TRIPLE, 256, 0, stream>>>(ipw, WB);
  qkv_mfma_kernel<<<(BB * SS / 128) * (TRIPLE / 128), 256, 0, stream>>>(LE, WB, ipb, QKV);
  attn_mfma_kernel<<<BB * NHH * (SS / 64), 256, 0, stream>>>(QKV, ctx);
  pooled_kernel<<<BB, 256, 0, stream>>>(ctx, opw, opb, out_pooled);
}

// Round 4
// 305.372 us; speedup vs baseline: 5.3364x; 1.0584x over previous
//
#include <hip/hip_runtime.h>
#include <hip/hip_bf16.h>

// Problem constants
#define BB 32
#define C1 128
#define SS 1024        // H*W
#define DD 256
#define NHH 8
#define DHH 32
#define KSEL 66        // ceil(0.0005*128*32*32)
#define TRIPLE 768
#define SELFLAG 0x40000000u

typedef __attribute__((ext_vector_type(8))) short bf16x8;
typedef __attribute__((ext_vector_type(4))) float f32x4;

__device__ inline short f2bf(float f) {
  union { __hip_bfloat16 h; unsigned short u; } c;
  c.h = __float2bfloat16(f);
  return (short)c.u;
}
__device__ inline float bf2f(short s) {
  union { float f; unsigned u; } c;
  c.u = ((unsigned)(unsigned short)s) << 16;
  return c.f;
}

// ---------------------------------------------------------------------------
// Kernel 1: 9x9 conv (cross-correlation, pad 4) + ReLU + fused level-1
// radix histogram (top 11 bits, zeros skipped) + per-batch max.
// ---------------------------------------------------------------------------
__global__ __launch_bounds__(256) void conv_relu_hist_kernel(
    const float* __restrict__ x, const float* __restrict__ w, float* __restrict__ A,
    unsigned* __restrict__ ghist1, unsigned* __restrict__ gmaxb) {
  const int bx = blockIdx.x;              // b*128 + c
  const int b = bx >> 7, c = bx & 127;
  __shared__ float xs[40 * 40];
  __shared__ float ws[81];
  __shared__ unsigned h[2048];
  __shared__ unsigned smax;
  const int t = threadIdx.x;
  for (int i = t; i < 1600; i += 256) {
    int r = i / 40, cc = i - r * 40;
    int gi = r - 4, gj = cc - 4;
    float v = 0.f;
    if (gi >= 0 && gi < 32 && gj >= 0 && gj < 32) v = x[(size_t)b * 1024 + gi * 32 + gj];
    xs[i] = v;
  }
  if (t < 81) ws[t] = w[(size_t)c * 81 + t];
  for (int i = t; i < 2048; i += 256) h[i] = 0u;
  if (t == 0) smax = 0u;
  __syncthreads();
  unsigned lmax = 0u;
#pragma unroll
  for (int i = 0; i < 4; ++i) {
    int p = t + i * 256;
    int r = p >> 5, col = p & 31;
    float acc = 0.f;
#pragma unroll
    for (int u = 0; u < 9; ++u)
#pragma unroll
      for (int v = 0; v < 9; ++v)
        acc += xs[(r + u) * 40 + col + v] * ws[u * 9 + v];
    acc = fmaxf(acc, 0.f);
    A[(size_t)bx * 1024 + p] = acc;
    unsigned bits = __float_as_uint(acc);
    if (bits > lmax) lmax = bits;
    if (bits >= (1u << 21)) atomicAdd(&h[bits >> 21], 1u);
  }
  atomicMax(&smax, lmax);
  __syncthreads();
  for (int i = t; i < 2048; i += 256)
    if (h[i]) atomicAdd(&ghist1[b * 2048 + i], h[i]);
  if (t == 0) atomicMax(&gmaxb[b], smax);
}

// ---------------------------------------------------------------------------
// Kernel 2a/2b: level-2 / level-3 radix histograms (rare-match passes)
// ---------------------------------------------------------------------------
__global__ __launch_bounds__(256) void hist2_kernel(
    const float* __restrict__ A, const unsigned* __restrict__ selv,
    unsigned* __restrict__ gh) {
  const int b = blockIdx.y, slice = blockIdx.x, t = threadIdx.x;
  const unsigned v1 = selv[b];
  __shared__ unsigned h[2048];
  for (int i = t; i < 2048; i += 256) h[i] = 0u;
  __syncthreads();
  const float* Ab = A + (size_t)b * (C1 * SS) + slice * 8192;
#pragma unroll 4
  for (int k = 0; k < 32; ++k) {
    unsigned bits = __float_as_uint(Ab[t + k * 256]);
    if ((bits >> 21) == v1) atomicAdd(&h[(bits >> 10) & 0x7FFu], 1u);
  }
  __syncthreads();
  for (int i = t; i < 2048; i += 256)
    if (h[i]) atomicAdd(&gh[b * 2048 + i], h[i]);
}

__global__ __launch_bounds__(256) void hist3_kernel(
    const float* __restrict__ A, const unsigned* __restrict__ selv,
    unsigned* __restrict__ gh) {
  const int b = blockIdx.y, slice = blockIdx.x, t = threadIdx.x;
  const unsigned pref = selv[b];
  __shared__ unsigned h[1024];
  for (int i = t; i < 1024; i += 256) h[i] = 0u;
  __syncthreads();
  const float* Ab = A + (size_t)b * (C1 * SS) + slice * 8192;
#pragma unroll 4
  for (int k = 0; k < 32; ++k) {
    unsigned bits = __float_as_uint(Ab[t + k * 256]);
    if ((bits >> 10) == pref) atomicAdd(&h[bits & 0x3FFu], 1u);
  }
  __syncthreads();
  for (int i = t; i < 1024; i += 256)
    if (h[i]) atomicAdd(&gh[b * 1024 + i], h[i]);
}

// ---------------------------------------------------------------------------
// Kernel 3: radix-level selection via parallel suffix scan. One block / batch.
// ---------------------------------------------------------------------------
__global__ __launch_bounds__(1024) void sel_kernel(
    const unsigned* __restrict__ gh, unsigned* __restrict__ selv,
    unsigned* __restrict__ selr, float* __restrict__ thresh,
    int nbins, int stage) {
  const int b = blockIdx.x, t = threadIdx.x;
  __shared__ unsigned hl[2048];
  __shared__ unsigned sfx[1024];
  unsigned r = (stage == 0) ? (unsigned)KSEL : selr[b];
  unsigned vold = (stage == 0) ? 0u : selv[b];
  if (nbins == 2048) {
    hl[t] = gh[b * 2048 + t];
    hl[t + 1024] = gh[b * 2048 + t + 1024];
  } else {
    hl[t] = gh[b * 1024 + t];
  }
  __syncthreads();
  sfx[t] = (nbins == 2048) ? (hl[2 * t] + hl[2 * t + 1]) : hl[t];
  __syncthreads();
  for (int off = 1; off < 1024; off <<= 1) {
    unsigned v = (t + off < 1024) ? sfx[t + off] : 0u;
    __syncthreads();
    sfx[t] += v;
    __syncthreads();
  }
  if ((stage != 0 && vold == SELFLAG) || sfx[0] < r) {
    if (t == 0) {
      if (stage == 2) thresh[b] = 0.0f;
      else { selv[b] = SELFLAG; selr[b] = r; }
    }
    return;
  }
  unsigned Snext = (t < 1023) ? sfx[t + 1] : 0u;
  if (nbins == 2048) {
    unsigned hi = hl[2 * t + 1], lo = hl[2 * t];
    if (Snext < r && Snext + hi >= r) {
      selv[b] = (vold << 11) | (unsigned)(2 * t + 1);
      selr[b] = r - Snext;
    } else if (Snext + hi < r && Snext + hi + lo >= r) {
      selv[b] = (vold << 11) | (unsigned)(2 * t);
      selr[b] = r - Snext - hi;
    }
  } else {
    if (Snext < r && sfx[t] >= r)
      thresh[b] = __uint_as_float((vold << 10) | (unsigned)t);
  }
}

// ---------------------------------------------------------------------------
// Kernel 4: per-pixel masked channel top-8 (jax tie-break semantics).
// ---------------------------------------------------------------------------
__global__ __launch_bounds__(256) void topk_pixel_kernel(
    const float* __restrict__ A, const float* __restrict__ thresh,
    const float* __restrict__ gmaxp, float* __restrict__ out_sw,
    float* __restrict__ out_topi, int* __restrict__ kidx, float* __restrict__ kval) {
  const int bx = blockIdx.x;              // b*4 + chunk
  const int b = bx >> 2;
  const int p = ((bx & 3) << 8) + threadIdx.x;
  const float th = thresh[b];
  const float gm = gmaxp[b];
  const float scale = gm > 0.f ? 1.f / gm : 0.f;
  const float* Ab = A + (size_t)b * (C1 * SS) + p;

  float tv0 = -1.f, tv1 = -1.f, tv2 = -1.f, tv3 = -1.f, tv4 = -1.f, tv5 = -1.f, tv6 = -1.f, tv7 = -1.f;
  int ti0 = 0, ti1 = 0, ti2 = 0, ti3 = 0, ti4 = 0, ti5 = 0, ti6 = 0, ti7 = 0;
  int cnt = 0;
#pragma unroll 1
  for (int c = 0; c < C1; ++c) {
    float v = Ab[(size_t)c << 10];
    if (v >= th) {
      ++cnt;
      bool s7 = v > tv6, p7 = (v > tv7) && !s7;
      float n7 = p7 ? v : (s7 ? tv6 : tv7); int m7 = p7 ? c : (s7 ? ti6 : ti7);
      bool s6 = v > tv5, p6 = (v > tv6) && !s6;
      float n6 = p6 ? v : (s6 ? tv5 : tv6); int m6 = p6 ? c : (s6 ? ti5 : ti6);
      bool s5 = v > tv4, p5 = (v > tv5) && !s5;
      float n5 = p5 ? v : (s5 ? tv4 : tv5); int m5 = p5 ? c : (s5 ? ti4 : ti5);
      bool s4 = v > tv3, p4 = (v > tv4) && !s4;
      float n4 = p4 ? v : (s4 ? tv3 : tv4); int m4 = p4 ? c : (s4 ? ti3 : ti4);
      bool s3 = v > tv2, p3 = (v > tv3) && !s3;
      float n3 = p3 ? v : (s3 ? tv2 : tv3); int m3 = p3 ? c : (s3 ? ti2 : ti3);
      bool s2 = v > tv1, p2 = (v > tv2) && !s2;
      float n2 = p2 ? v : (s2 ? tv1 : tv2); int m2 = p2 ? c : (s2 ? ti1 : ti2);
      bool s1 = v > tv0, p1 = (v > tv1) && !s1;
      float n1 = p1 ? v : (s1 ? tv0 : tv1); int m1 = p1 ? c : (s1 ? ti0 : ti1);
      bool p0 = v > tv0;
      float n0 = p0 ? v : tv0; int m0 = p0 ? c : ti0;
      tv7 = n7; ti7 = m7; tv6 = n6; ti6 = m6; tv5 = n5; ti5 = m5; tv4 = n4; ti4 = m4;
      tv3 = n3; ti3 = m3; tv2 = n2; ti2 = m2; tv1 = n1; ti1 = m1; tv0 = n0; ti0 = m0;
    }
  }
  const int m = cnt < 8 ? cnt : 8;
  int fv[8] = {ti0, ti1, ti2, ti3, ti4, ti5, ti6, ti7};
  int fill_c = 0;
#pragma unroll
  for (int j = 0; j < 8; ++j) {
    if (j >= m) {
      bool adv = true;
      while (adv) {
        adv = false;
#pragma unroll
        for (int t2 = 0; t2 < 8; ++t2)
          if (t2 < m && fv[t2] == fill_c) adv = true;
        if (adv) ++fill_c;
      }
      fv[j] = fill_c;
      ++fill_c;
    }
  }
  ti0 = fv[0]; ti1 = fv[1]; ti2 = fv[2]; ti3 = fv[3]; ti4 = fv[4]; ti5 = fv[5]; ti6 = fv[6]; ti7 = fv[7];
  if (m <= 0) tv0 = 0.f; if (m <= 1) tv1 = 0.f; if (m <= 2) tv2 = 0.f; if (m <= 3) tv3 = 0.f;
  if (m <= 4) tv4 = 0.f; if (m <= 5) tv5 = 0.f; if (m <= 6) tv6 = 0.f; if (m <= 7) tv7 = 0.f;

  const size_t pix = (size_t)b * SS + p;
  float* tp = out_topi + pix * 8;
  tp[0] = (float)ti0; tp[1] = (float)ti1; tp[2] = (float)ti2; tp[3] = (float)ti3;
  tp[4] = (float)ti4; tp[5] = (float)ti5; tp[6] = (float)ti6; tp[7] = (float)ti7;
  int* ki = kidx + pix * 8;
  ki[0] = ti0; ki[1] = ti1; ki[2] = ti2; ki[3] = ti3; ki[4] = ti4; ki[5] = ti5; ki[6] = ti6; ki[7] = ti7;
  float* kv = kval + pix * 8;
  float sv0 = tv0 * scale, sv1 = tv1 * scale, sv2 = tv2 * scale, sv3 = tv3 * scale;
  float sv4 = tv4 * scale, sv5 = tv5 * scale, sv6 = tv6 * scale, sv7 = tv7 * scale;
  kv[0] = sv0; kv[1] = sv1; kv[2] = sv2; kv[3] = sv3; kv[4] = sv4; kv[5] = sv5; kv[6] = sv6; kv[7] = sv7;
  float* sw = out_sw + pix * C1;
  if (m > 0) sw[ti0] = sv0; if (m > 1) sw[ti1] = sv1; if (m > 2) sw[ti2] = sv2; if (m > 3) sw[ti3] = sv3;
  if (m > 4) sw[ti4] = sv4; if (m > 5) sw[ti5] = sv5; if (m > 6) sw[ti6] = sv6; if (m > 7) sw[ti7] = sv7;
}

// ---------------------------------------------------------------------------
// Kernel 5: loc_emb(b,p,d) = PE(w,d) + sum_j kval[j]*emb[kidx[j], d] -> bf16
// ---------------------------------------------------------------------------
__global__ __launch_bounds__(256) void loc_emb_kernel(
    const int* __restrict__ kidx, const float* __restrict__ kval,
    const float* __restrict__ emb, unsigned short* __restrict__ le) {
  const int pix = blockIdx.x;             // b*1024 + p
  const int d = threadIdx.x;
  const int w = pix & 31;
  const int i2 = d >> 1;
  const float div = expf((float)(2 * i2) * (-9.210340371976184f / 256.f));
  const float ang = (float)w * div;
  const float pe = (d & 1) ? cosf(ang) : sinf(ang);
  const int* ki = kidx + (size_t)pix * 8;
  const float* kv = kval + (size_t)pix * 8;
  float acc = pe;
#pragma unroll
  for (int j = 0; j < 8; ++j) acc += kv[j] * emb[(size_t)ki[j] * DD + d];
  le[(size_t)pix * DD + d] = (unsigned short)f2bf(acc);
}

// ---------------------------------------------------------------------------
// Kernel 5b: in_proj_w fp32 -> bf16
// ---------------------------------------------------------------------------
__global__ __launch_bounds__(256) void w2bf_kernel(
    const float* __restrict__ W, unsigned short* __restrict__ Wb) {
  int i = blockIdx.x * 256 + threadIdx.x;
  Wb[i] = (unsigned short)f2bf(W[i]);
}

// ---------------------------------------------------------------------------
// Kernel 6: QKV(bf16) = LE @ Wb^T + bias.  128x128 tile, 2x2 waves, K-step 32.
// Staging remapped so each quarter-wave writes 16 distinct rows (bank-free);
// register prefetch hides global latency across the 8 K-steps.
// ---------------------------------------------------------------------------
__global__ __launch_bounds__(256) void qkv_mfma_kernel(
    const unsigned short* __restrict__ Xb, const unsigned short* __restrict__ Wb,
    const float* __restrict__ bias, unsigned short* __restrict__ Yb) {
  __shared__ __align__(16) short As[128][40];
  __shared__ __align__(16) short Bs[128][40];
  const int bid = blockIdx.x;                 // 1536 blocks = 8 * 192
  const int wgid = (bid & 7) * 192 + (bid >> 3);
  const int nt = wgid % 6, mt = wgid / 6;
  const int t = threadIdx.x;
  const int wv = t >> 6, lane = t & 63, lg = lane >> 4, ln = lane & 15;
  const int wm = wv >> 1, wn = wv & 1;

  // staging map: row = t&127, chunk c0 = (t>>7)*8 and c1 = c0+16 shorts
  const int srow = t & 127;
  const int sc0 = (t >> 7) * 8, sc1 = sc0 + 16;
  const unsigned short* xr = Xb + (size_t)(mt * 128 + srow) * DD;
  const unsigned short* wr = Wb + (size_t)(nt * 128 + srow) * DD;

  f32x4 acc[4][4];
#pragma unroll
  for (int i = 0; i < 4; ++i)
#pragma unroll
    for (int j = 0; j < 4; ++j) acc[i][j] = (f32x4){0, 0, 0, 0};

  bf16x8 xa0 = *(const bf16x8*)&xr[sc0];
  bf16x8 xa1 = *(const bf16x8*)&xr[sc1];
  bf16x8 wa0 = *(const bf16x8*)&wr[sc0];
  bf16x8 wa1 = *(const bf16x8*)&wr[sc1];

  for (int k0 = 0; k0 < DD; k0 += 32) {
    __syncthreads();
    *(bf16x8*)&As[srow][sc0] = xa0;
    *(bf16x8*)&As[srow][sc1] = xa1;
    *(bf16x8*)&Bs[srow][sc0] = wa0;
    *(bf16x8*)&Bs[srow][sc1] = wa1;
    if (k0 + 32 < DD) {
      xa0 = *(const bf16x8*)&xr[k0 + 32 + sc0];
      xa1 = *(const bf16x8*)&xr[k0 + 32 + sc1];
      wa0 = *(const bf16x8*)&wr[k0 + 32 + sc0];
      wa1 = *(const bf16x8*)&wr[k0 + 32 + sc1];
    }
    __syncthreads();
    bf16x8 af[4], bfr[4];
#pragma unroll
    for (int i = 0; i < 4; ++i) af[i] = *(const bf16x8*)&As[wm * 64 + i * 16 + ln][lg * 8];
#pragma unroll
    for (int j = 0; j < 4; ++j) bfr[j] = *(const bf16x8*)&Bs[wn * 64 + j * 16 + ln][lg * 8];
#pragma unroll
    for (int i = 0; i < 4; ++i)
#pragma unroll
      for (int j = 0; j < 4; ++j)
        acc[i][j] = __builtin_amdgcn_mfma_f32_16x16x32_bf16(af[i], bfr[j], acc[i][j], 0, 0, 0);
  }
#pragma unroll
  for (int i = 0; i < 4; ++i) {
#pragma unroll
    for (int j = 0; j < 4; ++j) {
      int col = nt * 128 + wn * 64 + j * 16 + ln;
      float bcol = bias[col];
#pragma unroll
      for (int r = 0; r < 4; ++r) {
        int row = mt * 128 + wm * 64 + i * 16 + lg * 4 + r;
        Yb[(size_t)row * TRIPLE + col] = (unsigned short)f2bf(acc[i][j][r] + bcol);
      }
    }
  }
}

// ---------------------------------------------------------------------------
// Kernel 7: bf16 MFMA flash attention, swapped QK^T (lane-local softmax).
// Staging remapped for bank-free LDS writes; register prefetch per tile;
// P written as packed dwords. Block = (b,h,64-q-chunk); 4 waves x 16 q.
// ---------------------------------------------------------------------------
__global__ __launch_bounds__(256) void attn_mfma_kernel(
    const unsigned short* __restrict__ QKV, float* __restrict__ ctx_sum) {
  const int bid = blockIdx.x;                 // 4096 blocks = 8 * 512
  const int wgid = (bid & 7) * 512 + (bid >> 3);
  const int qc = wgid & 15;
  const int h = (wgid >> 4) & 7;
  const int b = wgid >> 7;
  const int t = threadIdx.x;
  const int wv = t >> 6, lane = t & 63, lg = lane >> 4, ln = lane & 15;

  __shared__ __align__(16) short Ks[64][40];    // K tile [key][dh]
  __shared__ __align__(16) short Vt[32][72];    // V tile transposed [dh][key]
  __shared__ __align__(16) short Ps[4][16][72]; // P per wave [qrow][key]

  const size_t baseB = (size_t)b * SS * TRIPLE;
  const float scale = 0.17677669529663687f;     // 1/sqrt(32)
  // staging maps (bank-conflict-free):
  //   K: quarter-wave = 16 keys at fixed d-chunk
  const int keyK = (t & 15) | ((t >> 6) << 4);
  const int d0K = ((t >> 4) & 3) * 8;
  //   V: half-wave = 32 even/odd keys at fixed d-chunk -> write bank 4j+(t&31)
  const int keyV = ((t & 31) << 1) | (t >> 7);
  const int d0V = ((t >> 5) & 3) * 8;
  const unsigned short* kvbase = QKV + baseB + DD + h * DHH;

  // Q fragment (B-operand): col = ln (q), k = lg*8+j (dh); pre-scaled
  bf16x8 qf;
  {
    const unsigned short* qp = QKV + baseB + (size_t)(qc * 64 + wv * 16 + ln) * TRIPLE + h * DHH + lg * 8;
    bf16x8 qr = *(const bf16x8*)qp;
#pragma unroll
    for (int j = 0; j < 8; ++j) qf[j] = f2bf(bf2f(qr[j]) * scale);
  }
  float m = -1e30f, l = 0.f;                    // per-lane state for q = ln
  f32x4 acc[2] = {{0, 0, 0, 0}, {0, 0, 0, 0}};

  // prologue: load tile 0 into regs
  bf16x8 kreg = *(const bf16x8*)(kvbase + (size_t)keyK * TRIPLE + d0K);
  bf16x8 vreg = *(const bf16x8*)(kvbase + DD + (size_t)keyV * TRIPLE + d0V);

  for (int tile = 0; tile < 16; ++tile) {
    __syncthreads();
    *(bf16x8*)&Ks[keyK][d0K] = kreg;
#pragma unroll
    for (int j = 0; j < 8; ++j) Vt[d0V + j][keyV] = vreg[j];
    if (tile < 15) {
      kreg = *(const bf16x8*)(kvbase + (size_t)((tile + 1) * 64 + keyK) * TRIPLE + d0K);
      vreg = *(const bf16x8*)(kvbase + DD + (size_t)((tile + 1) * 64 + keyV) * TRIPLE + d0V);
    }
    __syncthreads();
    // swapped QK^T: S^T[key][q]; lane ln = q, regs over lg hold 16 of 64 keys
    f32x4 s[4];
#pragma unroll
    for (int st = 0; st < 4; ++st) {
      bf16x8 kf = *(const bf16x8*)&Ks[st * 16 + ln][lg * 8];
      s[st] = __builtin_amdgcn_mfma_f32_16x16x32_bf16(kf, qf, (f32x4){0, 0, 0, 0}, 0, 0, 0);
    }
    // lane-local online softmax for q = ln
    float mx = s[0][0];
#pragma unroll
    for (int st = 0; st < 4; ++st)
#pragma unroll
      for (int r = 0; r < 4; ++r) mx = fmaxf(mx, s[st][r]);
    mx = fmaxf(mx, __shfl_xor(mx, 16));
    mx = fmaxf(mx, __shfl_xor(mx, 32));
    float mn = fmaxf(m, mx);
    float corr = __expf(m - mn);
    m = mn;
    float ps = 0.f;
#pragma unroll
    for (int st = 0; st < 4; ++st)
#pragma unroll
      for (int r = 0; r < 4; ++r) {
        float p = __expf(s[st][r] - mn);
        s[st][r] = p;
        ps += p;
      }
    ps += __shfl_xor(ps, 16);
    ps += __shfl_xor(ps, 32);
    l = l * corr + ps;
    // P -> LDS as packed dwords: Ps[q=ln][key = st*16 + lg*4 + (2p,2p+1)]
    {
      unsigned* pr = (unsigned*)&Ps[wv][ln][0];
#pragma unroll
      for (int st = 0; st < 4; ++st)
#pragma unroll
        for (int p = 0; p < 2; ++p) {
          unsigned lo = (unsigned short)f2bf(s[st][2 * p]);
          unsigned hi = (unsigned short)f2bf(s[st][2 * p + 1]);
          pr[st * 8 + lg * 2 + p] = lo | (hi << 16);
        }
    }
    // rescale O accumulator rows (row q = lg*4 + r uses corr from lane q)
    float corrq[4];
#pragma unroll
    for (int r = 0; r < 4; ++r)
      corrq[r] = __shfl(corr, (lane & 48) | (lg * 4 + r));
#pragma unroll
    for (int sb = 0; sb < 2; ++sb)
#pragma unroll
      for (int r = 0; r < 4; ++r)
        acc[sb][r] *= corrq[r];
    // PV: O[16 q][32 d] += P[16 q][64 k] * V^T[32 d][64 k]
#pragma unroll
    for (int ks = 0; ks < 2; ++ks) {
      bf16x8 pa = *(const bf16x8*)&Ps[wv][ln][ks * 32 + lg * 8];
#pragma unroll
      for (int sb = 0; sb < 2; ++sb) {
        bf16x8 vb = *(const bf16x8*)&Vt[sb * 16 + ln][ks * 32 + lg * 8];
        acc[sb] = __builtin_amdgcn_mfma_f32_16x16x32_bf16(pa, vb, acc[sb], 0, 0, 0);
      }
    }
  }
  // normalize rows by 1/l(q), reduce over this wave's 16 q-rows, atomic add
  float invl = 1.f / l;
  float invq[4];
#pragma unroll
  for (int r = 0; r < 4; ++r)
    invq[r] = __shfl(invl, (lane & 48) | (lg * 4 + r));
#pragma unroll
  for (int sb = 0; sb < 2; ++sb) {
    float v = acc[sb][0] * invq[0] + acc[sb][1] * invq[1] +
              acc[sb][2] * invq[2] + acc[sb][3] * invq[3];
    v += __shfl_xor(v, 16);
    v += __shfl_xor(v, 32);
    if (lane < 16) atomicAdd(&ctx_sum[b * DD + h * DHH + sb * 16 + lane], v);
  }
}

// ---------------------------------------------------------------------------
// Kernel 8: pooled(b,o) = bias[o] + sum_d (ctx_sum[b,d]/1024) * Wout[o,d]
// ---------------------------------------------------------------------------
__global__ __launch_bounds__(256) void pooled_kernel(
    const float* __restrict__ ctx_sum, const float* __restrict__ Wout,
    const float* __restrict__ bout, float* __restrict__ out) {
  const int b = blockIdx.x;
  const int o = threadIdx.x;
  __shared__ float mc[DD];
  mc[o] = ctx_sum[b * DD + o] * (1.f / 1024.f);
  __syncthreads();
  float acc = bout[o];
  const float* wr = Wout + (size_t)o * DD;
#pragma unroll 4
  for (int d = 0; d < DD; ++d) acc += mc[d] * wr[d];
  out[b * DD + o] = acc;
}

// ---------------------------------------------------------------------------
extern "C" void kernel_launch(void* const* d_in, const int* in_sizes, int n_in,
                              void* d_out, int out_size, void* d_ws, size_t ws_size,
                              hipStream_t stream) {
  const float* x = (const float*)d_in[0];
  const float* conv_w = (const float*)d_in[1];
  const float* emb = (const float*)d_in[2];
  const float* ipw = (const float*)d_in[3];
  const float* ipb = (const float*)d_in[4];
  const float* opw = (const float*)d_in[5];
  const float* opb = (const float*)d_in[6];

  float* out = (float*)d_out;
  float* out_pooled = out;                          // 32*256       = 8192
  float* out_sw = out + 8192;                       // 32*32*32*128 = 4194304
  float* out_topi = out + 8192 + 4194304;           // 32*32*32*8   = 262144

  // workspace layout (~87 MiB)
  char* ws = (char*)d_ws;
  float*    A      = (float*)(ws);                      // 16777216 B
  unsigned* ghist1 = (unsigned*)(ws + 16777216);        // 262144 B
  unsigned* ghist2 = (unsigned*)(ws + 17039360);        // 262144 B
  unsigned* ghist3 = (unsigned*)(ws + 17301504);        // 131072 B
  unsigned* selv   = (unsigned*)(ws + 17432576);        // 128 B
  unsigned* selr   = (unsigned*)(ws + 17432704);        // 128 B
  float*    thresh = (float*)(ws + 17432832);           // 128 B
  unsigned* gmaxb  = (unsigned*)(ws + 17432960);        // 128 B
  int*      kidx   = (int*)(ws + 17433088);             // 1048576 B
  float*    kval   = (float*)(ws + 18481664);           // 1048576 B
  unsigned short* LE  = (unsigned short*)(ws + 19530240);   // 16777216 B
  unsigned short* QKV = (unsigned short*)(ws + 36307456);   // 50331648 B
  float*    ctx    = (float*)(ws + 86639104);           // 32768 B
  unsigned short* WB  = (unsigned short*)(ws + 86671872);   // 393216 B

  hipMemsetAsync(out_sw, 0, (size_t)4194304 * 4, stream);
  hipMemsetAsync(ws + 16777216, 0, 655872, stream);     // hists + sel + gmax
  hipMemsetAsync(ctx, 0, (size_t)BB * DD * 4, stream);

  conv_relu_hist_kernel<<<BB * C1, 256, 0, stream>>>(x, conv_w, A, ghist1, gmaxb);
  sel_kernel<<<BB, 1024, 0, stream>>>(ghist1, selv, selr, thresh, 2048, 0);
  hist2_kernel<<<dim3(16, BB), 256, 0, stream>>>(A, selv, ghist2);
  sel_kernel<<<BB, 1024, 0, stream>>>(ghist2, selv, selr, thresh, 2048, 1);
  hist3_kernel<<<dim3(16, BB), 256, 0, stream>>>(A, selv, ghist3);
  sel_kernel<<<BB, 1024, 0, stream>>>(ghist3, selv, selr, thresh, 1024, 2);
  topk_pixel_kernel<<<BB * 4, 256, 0, stream>>>(A, thresh, (const float*)gmaxb, out_sw, out_topi, kidx, kval);
  loc_emb_kernel<<<BB * SS, 256, 0, stream>>>(kidx, kval, emb, LE);
  w2bf_kernel<<<TRIPLE, 256, 0, stream>>>(ipw, WB);
  qkv_mfma_kernel<<<(BB * SS / 128) * (TRIPLE / 128), 256, 0, stream>>>(LE, WB, ipb, QKV);
  attn_mfma_kernel<<<BB * NHH * (SS / 64), 256, 0, stream>>>(QKV, ctx);
  pooled_kernel<<<BB, 256, 0, stream>>>(ctx, opw, opb, out_pooled);
}